// Round 14
// baseline (377.165 us; speedup 1.0000x reference)
//
#include <hip/hip_runtime.h>
#include <math.h>

#define SS 2048
#define HH 2048
#define HQ 16
#define HKV 4
#define GG 4
#define DD 128
#define KS 32
#define KSTRIDE 16
#define NCMP 127
#define NBLK 16
#define TOPK 8
#define WINSZ 512
#define TQ 16

typedef unsigned short u16;
typedef __bf16 bf16x8 __attribute__((ext_vector_type(8)));
typedef __bf16 bf16x4 __attribute__((ext_vector_type(4)));
typedef float f32x4 __attribute__((ext_vector_type(4)));

__device__ __forceinline__ u16 f2bf(float f) {
    __bf16 b = (__bf16)f;
    return __builtin_bit_cast(u16, b);
}

// XCD-aware bijective swizzle of a flattened block id (nwg must be %8==0)
__device__ __forceinline__ int xcd_swz(int id, int nwg) {
    if (nwg & 7) return id;
    int cpx = nwg >> 3;
    return (id & 7) * cpx + (id >> 3);
}

// ---------------- RoPE tables (llama3-style scaled inv freq) ----------------
__global__ void rope_tab(float* __restrict__ cost, float* __restrict__ sint) {
    int s = blockIdx.x;
    int i = threadIdx.x; // 0..63
    double inv = pow(500000.0, -(double)i / 64.0);
    double wav = 6.283185307179586476925286766559 / inv;
    double inv_s;
    if (wav > 8192.0) inv_s = inv / 8.0;
    else if (wav < 2048.0) inv_s = inv;
    else {
        double sm = (8192.0 / wav - 1.0) / 3.0;
        inv_s = (1.0 - sm) * inv / 8.0 + sm * inv;
    }
    float ang = (float)s * (float)inv_s; // reference computes angle in f32
    cost[s * 64 + i] = cosf(ang);
    sint[s * 64 + i] = sinf(ang);
}

// rope + optional scale + bf16 convert, fused
__global__ void rope_bf16(const float* __restrict__ src, u16* __restrict__ dst,
                          const float* __restrict__ cost, const float* __restrict__ sint,
                          int nh, float scale) {
    int s = blockIdx.x, h = blockIdx.y, i = threadIdx.x; // i<64
    const float* p = src + ((size_t)s * nh + h) * DD;
    float c = cost[s * 64 + i], sn = sint[s * 64 + i];
    float x1 = p[i], x2 = p[i + 64];
    u16* d = dst + ((size_t)s * nh + h) * DD;
    d[i] = f2bf((x1 * c - x2 * sn) * scale);
    d[i + 64] = f2bf((x2 * c + x1 * sn) * scale);
}

__global__ void sigmoid_k(float* __restrict__ x, int n) {
    int i = blockIdx.x * 256 + threadIdx.x;
    if (i < n) x[i] = 1.f / (1.f + __expf(-x[i]));
}

// ---------------- f32 -> bf16 flat convert (vec4) ----------------
__global__ void conv_bf16(const float* __restrict__ in, u16* __restrict__ out, int n4) {
    int i = blockIdx.x * 256 + threadIdx.x;
    if (i < n4) {
        float4 v = ((const float4*)in)[i];
        ushort4 o;
        o.x = f2bf(v.x); o.y = f2bf(v.y); o.z = f2bf(v.z); o.w = f2bf(v.w);
        ((ushort4*)out)[i] = o;
    }
}

// ---------------- v[s][h][d] f32 -> vt[h][d][s] bf16 ----------------
__global__ __launch_bounds__(256) void conv_vt(const float* __restrict__ v, u16* __restrict__ vt) {
    __shared__ float tile[32][33];
    int s0 = blockIdx.x * 32, d0 = blockIdx.y * 32, h = blockIdx.z;
    int tx = threadIdx.x & 31, ty = threadIdx.x >> 5;
#pragma unroll
    for (int i = 0; i < 32; i += 8)
        tile[ty + i][tx] = v[(size_t)(s0 + ty + i) * (HKV * DD) + h * DD + d0 + tx];
    __syncthreads();
#pragma unroll
    for (int i = 0; i < 32; i += 8)
        vt[(size_t)h * DD * SS + (size_t)(d0 + ty + i) * SS + s0 + tx] = f2bf(tile[tx][ty + i]);
}

// ---------------- convert + transpose: W[K][N] f32 -> Bt[Npad][K] bf16 (z-batched) ----
__global__ __launch_bounds__(256) void convT(const float* __restrict__ W, u16* __restrict__ Bt,
                                             int K, int N, int Npad,
                                             size_t wz, size_t bz) {
    __shared__ float tile[32][33];
    W += (size_t)blockIdx.z * wz;
    Bt += (size_t)blockIdx.z * bz;
    int bk = blockIdx.x * 32, bn = blockIdx.y * 32;
    int tx = threadIdx.x & 31, ty = threadIdx.x >> 5; // ty 0..7
#pragma unroll
    for (int i = 0; i < 32; i += 8) {
        int k = bk + ty + i, n = bn + tx;
        tile[ty + i][tx] = (n < N) ? W[(size_t)k * N + n] : 0.f;
    }
    __syncthreads();
#pragma unroll
    for (int i = 0; i < 32; i += 8) {
        int n = bn + ty + i, k = bk + tx;
        if (n < Npad) Bt[(size_t)n * K + k] = f2bf(tile[tx][ty + i]);
    }
}

// ---------------- bf16 MFMA GEMM: C[M,N] = A[M,K] @ Bt[N,K]^T ----------------
__device__ __forceinline__ void gload16(const void* g, void* l) {
    __builtin_amdgcn_global_load_lds((const __attribute__((address_space(1))) void*)g,
                                     (__attribute__((address_space(3))) void*)l, 16, 0, 0);
}

__global__ __launch_bounds__(256) void gemm_mfma(const u16* __restrict__ A,
                                                 const u16* __restrict__ Bt,
                                                 float* __restrict__ C,
                                                 int M, int N, int K) {
    __shared__ __align__(16) u16 Asm[128 * 64];
    __shared__ __align__(16) u16 Bsm[128 * 64];
    int t = threadIdx.x;
    int lane = t & 63;
    int w = t >> 6;
    int wm = w >> 1, wn = w & 1;
    // XCD-aware block swizzle (T1): bijective since nwg % 8 == 0 for our grids
    int nwg = gridDim.x * gridDim.y;
    int id = xcd_swz(blockIdx.y * gridDim.x + blockIdx.x, nwg);
    int bxs = id % gridDim.x, bys = id / gridDim.x;
    int bm = bys * 128, bn = bxs * 128;
    int lr = lane & 15, hi = lane >> 4;

    f32x4 acc[4][4] = {};
    for (int k0 = 0; k0 < K; k0 += 64) {
        if (k0) __syncthreads();
#pragma unroll
        for (int i = 0; i < 4; ++i) {
            int cflat = i * 256 + t;
            int m = cflat >> 3;
            int g = cflat & 7;
            int gl = g ^ (m & 7);
            unsigned lofs = (unsigned)((i * 256 + (t & ~63)) * 16);
            gload16(A + (size_t)(bm + m) * K + k0 + gl * 8, (char*)Asm + lofs);
            gload16(Bt + (size_t)(bn + m) * K + k0 + gl * 8, (char*)Bsm + lofs);
        }
        __syncthreads();
#pragma unroll
        for (int kk = 0; kk < 2; ++kk) {
            bf16x8 af[4], bf[4];
#pragma unroll
            for (int mi = 0; mi < 4; ++mi) {
                int row = wm * 64 + mi * 16 + lr;
                int g = (kk * 4 + hi) ^ (row & 7);
                af[mi] = *reinterpret_cast<const bf16x8*>(&Asm[row * 64 + g * 8]);
            }
#pragma unroll
            for (int ni = 0; ni < 4; ++ni) {
                int row = wn * 64 + ni * 16 + lr;
                int g = (kk * 4 + hi) ^ (row & 7);
                bf[ni] = *reinterpret_cast<const bf16x8*>(&Bsm[row * 64 + g * 8]);
            }
#pragma unroll
            for (int mi = 0; mi < 4; ++mi)
#pragma unroll
                for (int ni = 0; ni < 4; ++ni)
                    acc[mi][ni] = __builtin_amdgcn_mfma_f32_16x16x32_bf16(af[mi], bf[ni], acc[mi][ni], 0, 0, 0);
        }
    }
#pragma unroll
    for (int mi = 0; mi < 4; ++mi) {
#pragma unroll
        for (int ni = 0; ni < 4; ++ni) {
            int col = bn + wn * 64 + ni * 16 + lr;
            if (col < N) {
#pragma unroll
                for (int r = 0; r < 4; ++r) {
                    int row = bm + wm * 64 + mi * 16 + hi * 4 + r;
                    C[(size_t)row * N + col] = acc[mi][ni][r];
                }
            }
        }
    }
}

// ---------------- fused projection GEMM: x @ {Wq,Wk,Wv,Wg} in one dispatch ---------
__global__ __launch_bounds__(256) void gemm_proj(const u16* __restrict__ A,
                                                 const u16* __restrict__ BtQ,
                                                 const u16* __restrict__ BtK,
                                                 const u16* __restrict__ BtV,
                                                 const u16* __restrict__ BtG,
                                                 float* __restrict__ Cq,
                                                 float* __restrict__ Ck,
                                                 float* __restrict__ Cv,
                                                 float* __restrict__ Cg) {
    __shared__ __align__(16) u16 Asm[128 * 64];
    __shared__ __align__(16) u16 Bsm[128 * 64];
    // XCD-aware block swizzle (T1): nwg = 25*16 = 400, divisible by 8
    int nwg = gridDim.x * gridDim.y;
    int id = xcd_swz(blockIdx.y * gridDim.x + blockIdx.x, nwg);
    int bx = id % gridDim.x, by = id / gridDim.x;
    const u16* Bt; float* C; int N; int bn;
    if (bx < 16)      { Bt = BtQ; C = Cq; N = 2048; bn = bx * 128; }
    else if (bx < 20) { Bt = BtK; C = Ck; N = 512;  bn = (bx - 16) * 128; }
    else if (bx < 24) { Bt = BtV; C = Cv; N = 512;  bn = (bx - 20) * 128; }
    else              { Bt = BtG; C = Cg; N = 48;   bn = 0; }
    const int K = 2048;
    int t = threadIdx.x, lane = t & 63, w = t >> 6;
    int wm = w >> 1, wn = w & 1;
    int bm = by * 128;
    int lr = lane & 15, hi = lane >> 4;

    f32x4 acc[4][4] = {};
    for (int k0 = 0; k0 < K; k0 += 64) {
        if (k0) __syncthreads();
#pragma unroll
        for (int i = 0; i < 4; ++i) {
            int cflat = i * 256 + t;
            int m = cflat >> 3;
            int g = cflat & 7;
            int gl = g ^ (m & 7);
            unsigned lofs = (unsigned)((i * 256 + (t & ~63)) * 16);
            gload16(A + (size_t)(bm + m) * K + k0 + gl * 8, (char*)Asm + lofs);
            gload16(Bt + (size_t)(bn + m) * K + k0 + gl * 8, (char*)Bsm + lofs);
        }
        __syncthreads();
#pragma unroll
        for (int kk = 0; kk < 2; ++kk) {
            bf16x8 af[4], bf[4];
#pragma unroll
            for (int mi = 0; mi < 4; ++mi) {
                int row = wm * 64 + mi * 16 + lr;
                int g = (kk * 4 + hi) ^ (row & 7);
                af[mi] = *reinterpret_cast<const bf16x8*>(&Asm[row * 64 + g * 8]);
            }
#pragma unroll
            for (int ni = 0; ni < 4; ++ni) {
                int row = wn * 64 + ni * 16 + lr;
                int g = (kk * 4 + hi) ^ (row & 7);
                bf[ni] = *reinterpret_cast<const bf16x8*>(&Bsm[row * 64 + g * 8]);
            }
#pragma unroll
            for (int mi = 0; mi < 4; ++mi)
#pragma unroll
                for (int ni = 0; ni < 4; ++ni)
                    acc[mi][ni] = __builtin_amdgcn_mfma_f32_16x16x32_bf16(af[mi], bf[ni], acc[mi][ni], 0, 0, 0);
        }
    }
#pragma unroll
    for (int mi = 0; mi < 4; ++mi) {
#pragma unroll
        for (int ni = 0; ni < 4; ++ni) {
            int col = bn + wn * 64 + ni * 16 + lr;
            if (col < N) {
#pragma unroll
                for (int r = 0; r < 4; ++r) {
                    int row = bm + wm * 64 + mi * 16 + hi * 4 + r;
                    C[(size_t)row * N + col] = acc[mi][ni][r];
                }
            }
        }
    }
}

// ---------------- compressed K/V build, split-K (16 splits) ----------------
__global__ __launch_bounds__(256) void cmp_kv_split(const u16* __restrict__ Ak,
                                                    const u16* __restrict__ Wkt,
                                                    const u16* __restrict__ Av,
                                                    const u16* __restrict__ Wvt,
                                                    float* __restrict__ partials) {
    __shared__ __align__(16) u16 Asm[128 * 64];
    __shared__ __align__(16) u16 Bsm[128 * 64];
    int z = blockIdx.y, split = blockIdx.x;
    int h = z & 3;
    const u16* A  = (z >> 2) ? Av : Ak;
    const u16* Wt = (z >> 2) ? Wvt : Wkt;
    int t = threadIdx.x, lane = t & 63, w = t >> 6;
    int wm = w >> 1, wn = w & 1;
    int lr = lane & 15, hi = lane >> 4;
    const u16* Wh = Wt + (size_t)h * DD * (KS * DD);

    f32x4 acc[4][4] = {};
    int kbase = split * 256;
    for (int it = 0; it < 4; ++it) {
        int k0 = kbase + it * 64;
        if (it) __syncthreads();
        int roff = k0 >> 7;
        int dbase = ((k0 >> 6) & 1) * 64;
#pragma unroll
        for (int i = 0; i < 4; ++i) {
            int cflat = i * 256 + t;
            int m = cflat >> 3;
            int g = cflat & 7;
            int gl = g ^ (m & 7);
            unsigned lofs = (unsigned)((i * 256 + (t & ~63)) * 16);
            int nr = (m < NCMP) ? m : (NCMP - 1);   // clamp pad row
            gload16(A + ((size_t)(nr * KSTRIDE + roff) * HKV + h) * DD + dbase + gl * 8,
                    (char*)Asm + lofs);
            gload16(Wh + (size_t)m * (KS * DD) + k0 + gl * 8, (char*)Bsm + lofs);
        }
        __syncthreads();
#pragma unroll
        for (int kk = 0; kk < 2; ++kk) {
            bf16x8 af[4], bf[4];
#pragma unroll
            for (int mi = 0; mi < 4; ++mi) {
                int row = wm * 64 + mi * 16 + lr;
                int g = (kk * 4 + hi) ^ (row & 7);
                af[mi] = *reinterpret_cast<const bf16x8*>(&Asm[row * 64 + g * 8]);
            }
#pragma unroll
            for (int ni = 0; ni < 4; ++ni) {
                int row = wn * 64 + ni * 16 + lr;
                int g = (kk * 4 + hi) ^ (row & 7);
                bf[ni] = *reinterpret_cast<const bf16x8*>(&Bsm[row * 64 + g * 8]);
            }
#pragma unroll
            for (int mi = 0; mi < 4; ++mi)
#pragma unroll
                for (int ni = 0; ni < 4; ++ni)
                    acc[mi][ni] = __builtin_amdgcn_mfma_f32_16x16x32_bf16(af[mi], bf[ni], acc[mi][ni], 0, 0, 0);
        }
    }
    float* Cout = partials + ((size_t)(z * 16 + split)) * 128 * 128;
#pragma unroll
    for (int mi = 0; mi < 4; ++mi)
#pragma unroll
        for (int ni = 0; ni < 4; ++ni) {
            int col = wn * 64 + ni * 16 + lr;
#pragma unroll
            for (int r = 0; r < 4; ++r) {
                int row = wm * 64 + mi * 16 + hi * 4 + r;
                Cout[(size_t)row * 128 + col] = acc[mi][ni][r];
            }
        }
}

// reduce 16 splits -> bf16 ck [h][n][d] and bf16 cvT [h][d][n]
__global__ void cmp_kv_reduce(const float* __restrict__ partials,
                              u16* __restrict__ ckbf, u16* __restrict__ cvtbf) {
    int row = blockIdx.x, z = blockIdx.y, col = threadIdx.x; // 128 threads
    float s = 0.f;
#pragma unroll
    for (int sp = 0; sp < 16; ++sp)
        s += partials[(((size_t)z * 16 + sp) * 128 + row) * 128 + col];
    if (z < 4) ckbf[((size_t)z * 128 + row) * 128 + col] = f2bf(s);
    else       cvtbf[((size_t)(z - 4) * 128 + col) * 128 + row] = f2bf(s);
}

// ---------------- compressed attention via MFMA + block scores + top-8 -------------
__global__ __launch_bounds__(256) void cmp_attn_mfma(
    const u16* __restrict__ qbf,    // [S][HQ][D] bf16, pre-scaled
    const u16* __restrict__ ckbf,   // [HKV][128][128] bf16 (row 127 = pad)
    const u16* __restrict__ cvtbf,  // [HKV][128 d][128 n] bf16
    const float* __restrict__ gate,
    float* __restrict__ o_acc,
    unsigned int* __restrict__ sel) {
    __shared__ __align__(16) u16 Cks[128 * 128];   // 32 KB, swizzled ck
    __shared__ __align__(16) u16 P2[4][16 * 128];  // 16 KB per-wave P
    __shared__ float bs[4][16][16];                // 4 KB block-score partials
    int t = threadIdx.x, lane = t & 63, w = t >> 6;
    int lr = lane & 15, hi = lane >> 4;
    int s0 = blockIdx.x * 16, h = blockIdx.y;
    int hq = h * GG + w;
    int sr = s0 + lr;
    const u16* ckh = ckbf + (size_t)h * 128 * 128;
    const u16* cvh = cvtbf + (size_t)h * 128 * 128;
    bf16x8 qf[4];
#pragma unroll
    for (int ks = 0; ks < 4; ++ks)
        qf[ks] = *reinterpret_cast<const bf16x8*>(
            &qbf[((size_t)sr * HQ + hq) * DD + ks * 32 + hi * 8]);
    // stage ck into LDS: 16 chunks per 128-elem row, pre-swizzled global source
#pragma unroll
    for (int i = 0; i < 8; ++i) {
        int id = i * 256 + t;
        int key = id >> 4, sub = id & 15;
        gload16(ckh + (size_t)key * 128 + ((sub ^ (key & 7)) * 8),
                (char*)Cks + (id & ~63) * 16);
    }
    __syncthreads();
    f32x4 sacc[8] = {};
#pragma unroll
    for (int ks = 0; ks < 4; ++ks)
#pragma unroll
        for (int mt = 0; mt < 8; ++mt) {
            int row = mt * 16 + lr;
            bf16x8 kf = *reinterpret_cast<const bf16x8*>(
                &Cks[row * 128 + (((ks * 4 + hi) ^ (row & 7)) * 8)]);
            sacc[mt] = __builtin_amdgcn_mfma_f32_16x16x32_bf16(kf, qf[ks], sacc[mt], 0, 0, 0);
        }
    int nv = (sr >= 31) ? ((sr - 31) >> 4) + 1 : 0;
    float e[8][4];
    float mx = -1e30f;
#pragma unroll
    for (int mt = 0; mt < 8; ++mt)
#pragma unroll
        for (int r = 0; r < 4; ++r) {
            int n = mt * 16 + hi * 4 + r;
            float x = (n < nv) ? sacc[mt][r] : -1e30f;
            e[mt][r] = x;
            mx = fmaxf(mx, x);
        }
    mx = fmaxf(mx, __shfl_xor(mx, 16, 64));
    mx = fmaxf(mx, __shfl_xor(mx, 32, 64));
    float l = 0.f;
#pragma unroll
    for (int mt = 0; mt < 8; ++mt)
#pragma unroll
        for (int r = 0; r < 4; ++r) {
            int n = mt * 16 + hi * 4 + r;
            float p = (n < nv) ? __expf(e[mt][r] - mx) : 0.f;
            e[mt][r] = p;
            l += p;
        }
    l += __shfl_xor(l, 16, 64);
    l += __shfl_xor(l, 32, 64);
    float invl = (nv > 0) ? 1.f / l : 0.f;
#pragma unroll
    for (int mt = 0; mt < 8; ++mt)
#pragma unroll
        for (int r = 0; r < 4; ++r) e[mt][r] *= invl;
#pragma unroll
    for (int mt = 0; mt < 8; ++mt) {
        bf16x4 pk;
        pk[0] = (__bf16)e[mt][0]; pk[1] = (__bf16)e[mt][1];
        pk[2] = (__bf16)e[mt][2]; pk[3] = (__bf16)e[mt][3];
        int grp = mt * 2 + (hi >> 1);
        int idx = lr * 128 + ((grp ^ (lr & 7)) * 8) + (hi & 1) * 4;
        *reinterpret_cast<bf16x4*>(&P2[w][idx]) = pk;
    }
#pragma unroll
    for (int mt = 0; mt < 8; ++mt) {
        float s4 = e[mt][0] + e[mt][1] + e[mt][2] + e[mt][3];
        float v = s4 + __shfl_xor(s4, 16, 64);
        if (hi == 0) bs[w][lr][mt * 2] = v;
        else if (hi == 2) bs[w][lr][mt * 2 + 1] = v;
    }
    __syncthreads();
    bf16x8 pa[4];
#pragma unroll
    for (int kslot = 0; kslot < 4; ++kslot)
        pa[kslot] = *reinterpret_cast<const bf16x8*>(
            &P2[w][lr * 128 + (((kslot * 4 + hi) ^ (lr & 7)) * 8)]);
    f32x4 Os[8] = {};
#pragma unroll
    for (int nt = 0; nt < 8; ++nt) {
        int d = nt * 16 + lr;
#pragma unroll
        for (int kslot = 0; kslot < 4; ++kslot) {
            bf16x8 bv = *reinterpret_cast<const bf16x8*>(
                &cvh[(size_t)d * 128 + kslot * 32 + hi * 8]);
            Os[nt] = __builtin_amdgcn_mfma_f32_16x16x32_bf16(pa[kslot], bv, Os[nt], 0, 0, 0);
        }
    }
#pragma unroll
    for (int r = 0; r < 4; ++r) {
        int q = hi * 4 + r;
        int srow = s0 + q;
        float g0 = gate[((size_t)srow * HQ + hq) * 3 + 0];
#pragma unroll
        for (int nt = 0; nt < 8; ++nt) {
            size_t idx = ((size_t)srow * HQ + hq) * DD + nt * 16 + lr;
            o_acc[idx] = g0 * Os[nt][r];
        }
    }
    if (t < 16) {
        int q = t, s = s0 + q;
        int qblk = s >> 7;
#pragma unroll
        for (int b = 0; b < 16; ++b) {
            bool forced = (b == 0) || (b <= qblk && b > qblk - 2);
            bs[0][q][b] = bs[0][q][b] + bs[1][q][b] + bs[2][q][b] + bs[3][q][b]
                          + (forced ? 1e9f : 0.f);
        }
        unsigned int mask = 0;
        for (int it = 0; it < TOPK; ++it) {
            int arg = 0; float best = bs[0][q][0];
            for (int b = 1; b < 16; ++b) {
                float x = bs[0][q][b];
                if (x > best) { best = x; arg = b; }
            }
            mask |= 1u << arg;
            bs[0][q][arg] = -1e38f;
        }
        sel[s * HKV + h] = mask;
    }
}

// ---------------- selected + windowed attention, MFMA flash (GQA: 4 heads/block) ----
// Round-11 verified math + T14 async-STAGE split: next tile's K/V prefetched into
// registers (issued before compute, ds_written at next iteration's top), hiding
// L2/HBM latency under QK/softmax/PV. Same LDS (48.5 KB), (256,3).
__global__ __launch_bounds__(256, 3) void sel_win_mfma(
    const u16* __restrict__ qbf,   // [S][HQ][D] bf16, pre-scaled by 1/sqrt(D)
    const u16* __restrict__ kbf,   // [S][HKV][D] bf16
    const u16* __restrict__ vtbf,  // [HKV][D][S]  bf16 (transposed V)
    const float* __restrict__ gate,
    const unsigned int* __restrict__ sel,
    const float* __restrict__ oacc, // [S][HQ][D] f32 (g0*O_cmp)
    u16* __restrict__ outb) {       // [S][HQ][D] bf16
    __shared__ __align__(16) u16 Ks[64 * 128];          // [key][d-group swizzled]
    __shared__ __align__(16) u16 Vs[128 * 64];          // [d][key-group swizzled]
    __shared__ __align__(16) u16 P2[4][2][16 * 64];     // per-wave, per-plane P[q][key swz]
    __shared__ unsigned int sml[16];
    int t = threadIdx.x, lane = t & 63, w = t >> 6;
    int lr = lane & 15, hi = lane >> 4;
    int s0 = (gridDim.x - 1 - blockIdx.x) * 16;         // heavy tiles first
    int h = blockIdx.y;
    int hq = h * GG + w;
    int sr = s0 + lr;             // q row this lane handles in softmax role
    if (t < 16) sml[t] = sel[(s0 + t) * HKV + h];
    bf16x8 qf[4];
#pragma unroll
    for (int ks = 0; ks < 4; ++ks)
        qf[ks] = *reinterpret_cast<const bf16x8*>(
            &qbf[((size_t)(s0 + lr) * HQ + hq) * DD + ks * 32 + hi * 8]);
    __syncthreads();
    unsigned mymask = sml[lr];
    unsigned orMask = 0;
#pragma unroll
    for (int i = 0; i < 16; ++i) orMask |= sml[i];
    float m_u = -1e30f, l_s = 0.f, l_w = 0.f;
    f32x4 Os[8] = {}, Ow[8] = {};
    int smax = s0 + 15;
    const u16* vbase = vtbf + (size_t)h * DD * SS;

    // wave-uniform activity test for a 64-key half-tile at position p
    auto isActive = [&](int p) -> bool {
        int kb = p >> 7;
        bool ns = (orMask >> kb) & 1u;
        bool hw = (p + 63 >= s0 - (WINSZ - 1));
        return ns || hw;
    };
    // staging registers (T14): next tile's K/V, 32 VGPRs
    bf16x8 kreg[4], vreg[4];
    // find first active tile and issue its loads
    int hst = 0;
    while (hst <= smax && !isActive(hst)) hst += 64;
#pragma unroll
    for (int i = 0; i < 4; ++i) {
        int id = i * 256 + t;
        int key = id >> 4, dq = id & 15;
        kreg[i] = *reinterpret_cast<const bf16x8*>(
            &kbf[((size_t)(hst + key) * HKV + h) * DD + ((dq ^ (key & 7)) * 8)]);
        int d = id >> 3, kq = id & 7;
        vreg[i] = *reinterpret_cast<const bf16x8*>(
            &vbase[(size_t)d * SS + hst + ((kq ^ (d & 7)) * 8)]);
    }

    while (hst <= smax) {
        int nxt = hst + 64;
        while (nxt <= smax && !isActive(nxt)) nxt += 64;
        __syncthreads();   // prior iteration's PV done with Ks/Vs
        // write staged regs to LDS (linear chunk layout, same as gload_lds dest)
#pragma unroll
        for (int i = 0; i < 4; ++i) {
            int id = i * 256 + t;
            *reinterpret_cast<bf16x8*>((char*)Ks + id * 16) = kreg[i];
            *reinterpret_cast<bf16x8*>((char*)Vs + id * 16) = vreg[i];
        }
        __syncthreads();   // staging visible
        // prefetch next tile into regs NOW; latency hides under compute below
        if (nxt <= smax) {
#pragma unroll
            for (int i = 0; i < 4; ++i) {
                int id = i * 256 + t;
                int key = id >> 4, dq = id & 15;
                kreg[i] = *reinterpret_cast<const bf16x8*>(
                    &kbf[((size_t)(nxt + key) * HKV + h) * DD + ((dq ^ (key & 7)) * 8)]);
                int d = id >> 3, kq = id & 7;
                vreg[i] = *reinterpret_cast<const bf16x8*>(
                    &vbase[(size_t)d * SS + nxt + ((kq ^ (d & 7)) * 8)]);
            }
        }
        int kb = hst >> 7;
        bool needSel = (orMask >> kb) & 1u;
        bool selbit = needSel && ((mymask >> kb) & 1u);
        bool hWin = (hst + 63 >= s0 - (WINSZ - 1));
        f32x4 sacc[4] = {};
        __builtin_amdgcn_s_setprio(1);
#pragma unroll
        for (int ks = 0; ks < 4; ++ks) {
#pragma unroll
            for (int mt = 0; mt < 4; ++mt) {
                int key = mt * 16 + lr;
                bf16x8 kf = *reinterpret_cast<const bf16x8*>(
                    &Ks[key * 128 + (((ks * 4 + hi) ^ (key & 7)) * 8)]);
                sacc[mt] = __builtin_amdgcn_mfma_f32_16x16x32_bf16(kf, qf[ks], sacc[mt], 0, 0, 0);
            }
        }
        __builtin_amdgcn_s_setprio(0);
        // shared-max softmax over the union mask
        float e4[4][4];
        float mx = -1e30f;
#pragma unroll
        for (int mt = 0; mt < 4; ++mt)
#pragma unroll
            for (int r = 0; r < 4; ++r) {
                int key = hst + mt * 16 + hi * 4 + r;
                bool vS = selbit && (key <= sr);
                bool vW = hWin && (key <= sr) && (key > sr - WINSZ);
                float e = (vS || vW) ? sacc[mt][r] : -1e30f;
                e4[mt][r] = e;
                mx = fmaxf(mx, e);
            }
        mx = fmaxf(mx, __shfl_xor(mx, 16, 64));
        mx = fmaxf(mx, __shfl_xor(mx, 32, 64));
        if (!__all(mx - m_u <= 8.f)) {
            float newm = fmaxf(m_u, mx);
            float corr = __expf(m_u - newm);
            m_u = newm;
            l_s *= corr; l_w *= corr;
#pragma unroll
            for (int r = 0; r < 4; ++r) {
                float c2 = __shfl(corr, hi * 4 + r, 64);
#pragma unroll
                for (int nt = 0; nt < 8; ++nt) { Os[nt][r] *= c2; Ow[nt][r] *= c2; }
            }
        }
        float lsA = 0.f, lwA = 0.f;
#pragma unroll
        for (int mt = 0; mt < 4; ++mt)
#pragma unroll
            for (int r = 0; r < 4; ++r) {
                int key = hst + mt * 16 + hi * 4 + r;
                bool vS = selbit && (key <= sr);
                bool vW = hWin && (key <= sr) && (key > sr - WINSZ);
                float e = (vS || vW) ? __expf(e4[mt][r] - m_u) : 0.f;
                e4[mt][r] = e;
                lsA += vS ? e : 0.f;
                lwA += vW ? e : 0.f;
            }
        lsA += __shfl_xor(lsA, 16, 64); lsA += __shfl_xor(lsA, 32, 64);
        lwA += __shfl_xor(lwA, 16, 64); lwA += __shfl_xor(lwA, 32, 64);
        l_s += lsA; l_w += lwA;
        if (needSel) {
#pragma unroll
            for (int mt = 0; mt < 4; ++mt) {
                bf16x4 pk;
#pragma unroll
                for (int r = 0; r < 4; ++r) {
                    int key = hst + mt * 16 + hi * 4 + r;
                    bool vS = selbit && (key <= sr);
                    pk[r] = (__bf16)(vS ? e4[mt][r] : 0.f);
                }
                int grp = mt * 2 + (hi >> 1);
                int idx = lr * 64 + ((grp ^ (lr & 7)) * 8) + (hi & 1) * 4;
                *reinterpret_cast<bf16x4*>(&P2[w][0][idx]) = pk;
            }
        }
        if (hWin) {
#pragma unroll
            for (int mt = 0; mt < 4; ++mt) {
                bf16x4 pk;
#pragma unroll
                for (int r = 0; r < 4; ++r) {
                    int key = hst + mt * 16 + hi * 4 + r;
                    bool vW = (key <= sr) && (key > sr - WINSZ);
                    pk[r] = (__bf16)(vW ? e4[mt][r] : 0.f);
                }
                int grp = mt * 2 + (hi >> 1);
                int idx = lr * 64 + ((grp ^ (lr & 7)) * 8) + (hi & 1) * 4;
                *reinterpret_cast<bf16x4*>(&P2[w][1][idx]) = pk;
            }
        }
        bf16x8 pas0, pas1, paw0, paw1;
        if (needSel) {
            pas0 = *reinterpret_cast<const bf16x8*>(&P2[w][0][lr * 64 + (((0 + hi) ^ (lr & 7)) * 8)]);
            pas1 = *reinterpret_cast<const bf16x8*>(&P2[w][0][lr * 64 + (((4 + hi) ^ (lr & 7)) * 8)]);
        }
        if (hWin) {
            paw0 = *reinterpret_cast<const bf16x8*>(&P2[w][1][lr * 64 + (((0 + hi) ^ (lr & 7)) * 8)]);
            paw1 = *reinterpret_cast<const bf16x8*>(&P2[w][1][lr * 64 + (((4 + hi) ^ (lr & 7)) * 8)]);
        }
        __builtin_amdgcn_s_setprio(1);
#pragma unroll
        for (int nt = 0; nt < 8; ++nt) {
            int d = nt * 16 + lr;
            bf16x8 bv0 = *reinterpret_cast<const bf16x8*>(&Vs[d * 64 + (((0 + hi) ^ (d & 7)) * 8)]);
            bf16x8 bv1 = *reinterpret_cast<const bf16x8*>(&Vs[d * 64 + (((4 + hi) ^ (d & 7)) * 8)]);
            if (needSel) {
                Os[nt] = __builtin_amdgcn_mfma_f32_16x16x32_bf16(pas0, bv0, Os[nt], 0, 0, 0);
                Os[nt] = __builtin_amdgcn_mfma_f32_16x16x32_bf16(pas1, bv1, Os[nt], 0, 0, 0);
            }
            if (hWin) {
                Ow[nt] = __builtin_amdgcn_mfma_f32_16x16x32_bf16(paw0, bv0, Ow[nt], 0, 0, 0);
                Ow[nt] = __builtin_amdgcn_mfma_f32_16x16x32_bf16(paw1, bv1, Ow[nt], 0, 0, 0);
            }
        }
        __builtin_amdgcn_s_setprio(0);
        hst = nxt;
    }
    // epilogue: rows q = hi*4+r, cols d = nt*16+lr; combine with cmp (f32) -> bf16
    float invls = (l_s > 0.f) ? 1.f / l_s : 0.f;
    float invlw = (l_w > 0.f) ? 1.f / l_w : 0.f;
#pragma unroll
    for (int r = 0; r < 4; ++r) {
        int q = hi * 4 + r;
        int srow = s0 + q;
        float a1 = gate[((size_t)srow * HQ + hq) * 3 + 1] * __shfl(invls, q, 64);
        float a2 = gate[((size_t)srow * HQ + hq) * 3 + 2] * __shfl(invlw, q, 64);
#pragma unroll
        for (int nt = 0; nt < 8; ++nt) {
            size_t idx = ((size_t)srow * HQ + hq) * DD + nt * 16 + lr;
            outb[idx] = f2bf(oacc[idx] + a1 * Os[nt][r] + a2 * Ow[nt][r]);
        }
    }
}

extern "C" void kernel_launch(void* const* d_in, const int* in_sizes, int n_in,
                              void* d_out, int out_size, void* d_ws, size_t ws_size,
                              hipStream_t stream) {
    const float* x   = (const float*)d_in[0];
    const float* Wq  = (const float*)d_in[1];
    const float* Wk  = (const float*)d_in[2];
    const float* Wv  = (const float*)d_in[3];
    const float* Wo  = (const float*)d_in[4];
    const float* Wg  = (const float*)d_in[5];
    const float* Wck = (const float*)d_in[6];
    const float* Wcv = (const float*)d_in[7];
    float* out = (float*)d_out;
    char* w = (char*)d_ws;
    float* qb   = (float*)(w + 0);          // 16 MiB f32 q GEMM out
    float* kb   = (float*)(w + 16777216);   // 4 MiB f32 k out; later vbf
    float* vb   = (float*)(w + 20971520);   // 4 MiB f32 v out
    float* g3   = (float*)(w + 25165824);   // gates
    u16* ckbf   = (u16*)(w + 25559040);     // [4][128][128] bf16 = 128 KiB
    u16* cvtbf  = (u16*)(w + 25819136);     // [4][128 d][128 n] bf16 = 128 KiB
    unsigned int* selb = (unsigned int*)(w + 26079232);
    float* cost = (float*)(w + 26112000);
    float* sint = (float*)(w + 26636288);
    float* oacc = (float*)(w + 27160576);   // 16 MiB; first 8 MiB doubles as partials
    u16* xb     = (u16*)(w + 43937792);     // 8 MiB; later Wcv_t
    u16* oaccb  = (u16*)(w + 52326400);     // 8 MiB; earlier Wck_t, later attn bf16 out
    u16* Wq_t   = (u16*)(w + 60715008);     // 8 MiB; later qbf
    u16* Wo_t   = (u16*)(w + 69103616);     // 8 MiB
    u16* Wk_t   = (u16*)(w + 77492224);     // 2 MiB; later kbf
    u16* Wv_t   = (u16*)(w + 79589376);     // 2 MiB; later vtbf
    u16* Wg_t   = (u16*)(w + 81686528);     // 0.5 MiB
    u16* qbf = Wq_t;
    u16* kbf = Wk_t;
    u16* vtbf = Wv_t;
    u16* vbf = (u16*)kb;                    // kb dead after rope_k
    u16* Wck_t = oaccb;                     // dead before sel_win writes oaccb
    u16* Wcv_t = xb;                        // xb dead after gemm_proj
    float* partials = oacc;                 // consumed before cmp_attn writes oacc

    hipLaunchKernelGGL(rope_tab, dim3(SS), dim3(64), 0, stream, cost, sint);
    hipLaunchKernelGGL(conv_bf16, dim3(4096), dim3(256), 0, stream, x, xb, SS * HH / 4);
    hipLaunchKernelGGL(convT, dim3(64, 64), dim3(256), 0, stream, Wq, Wq_t, HH, 2048, 2048, 0, 0);
    hipLaunchKernelGGL(convT, dim3(64, 16), dim3(256), 0, stream, Wk, Wk_t, HH, 512, 512, 0, 0);
    hipLaunchKernelGGL(convT, dim3(64, 16), dim3(256), 0, stream, Wv, Wv_t, HH, 512, 512, 0, 0);
    hipLaunchKernelGGL(convT, dim3(64, 4),  dim3(256), 0, stream, Wg, Wg_t, HH, 48, 128, 0, 0);
    hipLaunchKernelGGL(convT, dim3(64, 64), dim3(256), 0, stream, Wo, Wo_t, HQ * DD, 2048, 2048, 0, 0);
    // fused projections
    hipLaunchKernelGGL(gemm_proj, dim3(25, 16), dim3(256), 0, stream,
                       xb, Wq_t, Wk_t, Wv_t, Wg_t, qb, kb, vb, g3);
    // rope + scale + bf16 (q), rope + bf16 (k)
    hipLaunchKernelGGL(rope_bf16, dim3(SS, HQ),  dim3(64), 0, stream, qb, qbf, cost, sint, HQ, 0.08838834764831845f);
    hipLaunchKernelGGL(rope_bf16, dim3(SS, HKV), dim3(64), 0, stream, kb, kbf, cost, sint, HKV, 1.0f);
    hipLaunchKernelGGL(sigmoid_k, dim3((SS * HQ * 3 + 255) / 256), dim3(256), 0, stream, g3, SS * HQ * 3);
    hipLaunchKernelGGL(conv_bf16, dim3(1024), dim3(256), 0, stream, vb, vbf, SS * HKV * DD / 4);
    hipLaunchKernelGGL(conv_vt, dim3(64, 4, 4), dim3(256), 0, stream, vb, vtbf);
    // Wck/Wcv -> transposed bf16 (z-batched over h)
    hipLaunchKernelGGL(convT, dim3(128, 4, 4), dim3(256), 0, stream,
                       Wck, Wck_t, KS * DD, DD, DD, (size_t)KS * DD * DD, (size_t)DD * KS * DD);
    hipLaunchKernelGGL(convT, dim3(128, 4, 4), dim3(256), 0, stream,
                       Wcv, Wcv_t, KS * DD, DD, DD, (size_t)KS * DD * DD, (size_t)DD * KS * DD);
    // compressed K/V: split-K MFMA + reduce to bf16 ck / cvT
    hipLaunchKernelGGL(cmp_kv_split, dim3(16, 8), dim3(256), 0, stream,
                       kbf, Wck_t, vbf, Wcv_t, partials);
    hipLaunchKernelGGL(cmp_kv_reduce, dim3(128, 8), dim3(128), 0, stream,
                       partials, ckbf, cvtbf);
    // attention (two-kernel structure; sel_win combines + writes bf16 out)
    hipLaunchKernelGGL(cmp_attn_mfma, dim3(SS / TQ, HKV), dim3(256), 0, stream,
                       qbf, ckbf, cvtbf, g3, oacc, selb);
    hipLaunchKernelGGL(sel_win_mfma, dim3(SS / TQ, HKV), dim3(256), 0, stream,
                       qbf, kbf, vtbf, g3, selb, oacc, oaccb);
    // output projection
    hipLaunchKernelGGL(gemm_mfma, dim3(16, 16), dim3(256), 0, stream, oaccb, Wo_t, out, 2048, 2048, 2048);
}

// Round 15
// 264.831 us; speedup vs baseline: 1.4242x; 1.4242x over previous
//
#include <hip/hip_runtime.h>
#include <math.h>

#define SS 2048
#define HH 2048
#define HQ 16
#define HKV 4
#define GG 4
#define DD 128
#define KS 32
#define KSTRIDE 16
#define NCMP 127
#define NBLK 16
#define TOPK 8
#define WINSZ 512
#define TQ 16

typedef unsigned short u16;
typedef __bf16 bf16x8 __attribute__((ext_vector_type(8)));
typedef __bf16 bf16x4 __attribute__((ext_vector_type(4)));
typedef float f32x4 __attribute__((ext_vector_type(4)));

__device__ __forceinline__ u16 f2bf(float f) {
    __bf16 b = (__bf16)f;
    return __builtin_bit_cast(u16, b);
}

// XCD-aware bijective swizzle of a flattened block id (nwg must be %8==0)
__device__ __forceinline__ int xcd_swz(int id, int nwg) {
    if (nwg & 7) return id;
    int cpx = nwg >> 3;
    return (id & 7) * cpx + (id >> 3);
}

// ---------------- RoPE tables (llama3-style scaled inv freq) ----------------
__global__ void rope_tab(float* __restrict__ cost, float* __restrict__ sint) {
    int s = blockIdx.x;
    int i = threadIdx.x; // 0..63
    double inv = pow(500000.0, -(double)i / 64.0);
    double wav = 6.283185307179586476925286766559 / inv;
    double inv_s;
    if (wav > 8192.0) inv_s = inv / 8.0;
    else if (wav < 2048.0) inv_s = inv;
    else {
        double sm = (8192.0 / wav - 1.0) / 3.0;
        inv_s = (1.0 - sm) * inv / 8.0 + sm * inv;
    }
    float ang = (float)s * (float)inv_s; // reference computes angle in f32
    cost[s * 64 + i] = cosf(ang);
    sint[s * 64 + i] = sinf(ang);
}

// rope + optional scale + bf16 convert, fused
__global__ void rope_bf16(const float* __restrict__ src, u16* __restrict__ dst,
                          const float* __restrict__ cost, const float* __restrict__ sint,
                          int nh, float scale) {
    int s = blockIdx.x, h = blockIdx.y, i = threadIdx.x; // i<64
    const float* p = src + ((size_t)s * nh + h) * DD;
    float c = cost[s * 64 + i], sn = sint[s * 64 + i];
    float x1 = p[i], x2 = p[i + 64];
    u16* d = dst + ((size_t)s * nh + h) * DD;
    d[i] = f2bf((x1 * c - x2 * sn) * scale);
    d[i + 64] = f2bf((x2 * c + x1 * sn) * scale);
}

__global__ void sigmoid_k(float* __restrict__ x, int n) {
    int i = blockIdx.x * 256 + threadIdx.x;
    if (i < n) x[i] = 1.f / (1.f + __expf(-x[i]));
}

// ---------------- f32 -> bf16 flat convert (vec4) ----------------
__global__ void conv_bf16(const float* __restrict__ in, u16* __restrict__ out, int n4) {
    int i = blockIdx.x * 256 + threadIdx.x;
    if (i < n4) {
        float4 v = ((const float4*)in)[i];
        ushort4 o;
        o.x = f2bf(v.x); o.y = f2bf(v.y); o.z = f2bf(v.z); o.w = f2bf(v.w);
        ((ushort4*)out)[i] = o;
    }
}

// ---------------- v[s][h][d] f32 -> vt[h][d][s] bf16 ----------------
__global__ __launch_bounds__(256) void conv_vt(const float* __restrict__ v, u16* __restrict__ vt) {
    __shared__ float tile[32][33];
    int s0 = blockIdx.x * 32, d0 = blockIdx.y * 32, h = blockIdx.z;
    int tx = threadIdx.x & 31, ty = threadIdx.x >> 5;
#pragma unroll
    for (int i = 0; i < 32; i += 8)
        tile[ty + i][tx] = v[(size_t)(s0 + ty + i) * (HKV * DD) + h * DD + d0 + tx];
    __syncthreads();
#pragma unroll
    for (int i = 0; i < 32; i += 8)
        vt[(size_t)h * DD * SS + (size_t)(d0 + ty + i) * SS + s0 + tx] = f2bf(tile[tx][ty + i]);
}

// ---------------- convert + transpose: W[K][N] f32 -> Bt[Npad][K] bf16 (z-batched) ----
__global__ __launch_bounds__(256) void convT(const float* __restrict__ W, u16* __restrict__ Bt,
                                             int K, int N, int Npad,
                                             size_t wz, size_t bz) {
    __shared__ float tile[32][33];
    W += (size_t)blockIdx.z * wz;
    Bt += (size_t)blockIdx.z * bz;
    int bk = blockIdx.x * 32, bn = blockIdx.y * 32;
    int tx = threadIdx.x & 31, ty = threadIdx.x >> 5; // ty 0..7
#pragma unroll
    for (int i = 0; i < 32; i += 8) {
        int k = bk + ty + i, n = bn + tx;
        tile[ty + i][tx] = (n < N) ? W[(size_t)k * N + n] : 0.f;
    }
    __syncthreads();
#pragma unroll
    for (int i = 0; i < 32; i += 8) {
        int n = bn + ty + i, k = bk + tx;
        if (n < Npad) Bt[(size_t)n * K + k] = f2bf(tile[tx][ty + i]);
    }
}

// ---------------- bf16 MFMA GEMM: C[M,N] = A[M,K] @ Bt[N,K]^T ----------------
__device__ __forceinline__ void gload16(const void* g, void* l) {
    __builtin_amdgcn_global_load_lds((const __attribute__((address_space(1))) void*)g,
                                     (__attribute__((address_space(3))) void*)l, 16, 0, 0);
}

__global__ __launch_bounds__(256) void gemm_mfma(const u16* __restrict__ A,
                                                 const u16* __restrict__ Bt,
                                                 float* __restrict__ C,
                                                 int M, int N, int K) {
    __shared__ __align__(16) u16 Asm[128 * 64];
    __shared__ __align__(16) u16 Bsm[128 * 64];
    int t = threadIdx.x;
    int lane = t & 63;
    int w = t >> 6;
    int wm = w >> 1, wn = w & 1;
    // XCD-aware block swizzle (T1): bijective since nwg % 8 == 0 for our grids
    int nwg = gridDim.x * gridDim.y;
    int id = xcd_swz(blockIdx.y * gridDim.x + blockIdx.x, nwg);
    int bxs = id % gridDim.x, bys = id / gridDim.x;
    int bm = bys * 128, bn = bxs * 128;
    int lr = lane & 15, hi = lane >> 4;

    f32x4 acc[4][4] = {};
    for (int k0 = 0; k0 < K; k0 += 64) {
        if (k0) __syncthreads();
#pragma unroll
        for (int i = 0; i < 4; ++i) {
            int cflat = i * 256 + t;
            int m = cflat >> 3;
            int g = cflat & 7;
            int gl = g ^ (m & 7);
            unsigned lofs = (unsigned)((i * 256 + (t & ~63)) * 16);
            gload16(A + (size_t)(bm + m) * K + k0 + gl * 8, (char*)Asm + lofs);
            gload16(Bt + (size_t)(bn + m) * K + k0 + gl * 8, (char*)Bsm + lofs);
        }
        __syncthreads();
#pragma unroll
        for (int kk = 0; kk < 2; ++kk) {
            bf16x8 af[4], bf[4];
#pragma unroll
            for (int mi = 0; mi < 4; ++mi) {
                int row = wm * 64 + mi * 16 + lr;
                int g = (kk * 4 + hi) ^ (row & 7);
                af[mi] = *reinterpret_cast<const bf16x8*>(&Asm[row * 64 + g * 8]);
            }
#pragma unroll
            for (int ni = 0; ni < 4; ++ni) {
                int row = wn * 64 + ni * 16 + lr;
                int g = (kk * 4 + hi) ^ (row & 7);
                bf[ni] = *reinterpret_cast<const bf16x8*>(&Bsm[row * 64 + g * 8]);
            }
#pragma unroll
            for (int mi = 0; mi < 4; ++mi)
#pragma unroll
                for (int ni = 0; ni < 4; ++ni)
                    acc[mi][ni] = __builtin_amdgcn_mfma_f32_16x16x32_bf16(af[mi], bf[ni], acc[mi][ni], 0, 0, 0);
        }
    }
#pragma unroll
    for (int mi = 0; mi < 4; ++mi) {
#pragma unroll
        for (int ni = 0; ni < 4; ++ni) {
            int col = bn + wn * 64 + ni * 16 + lr;
            if (col < N) {
#pragma unroll
                for (int r = 0; r < 4; ++r) {
                    int row = bm + wm * 64 + mi * 16 + hi * 4 + r;
                    C[(size_t)row * N + col] = acc[mi][ni][r];
                }
            }
        }
    }
}

// ---------------- fused projection GEMM: x @ {Wq,Wk,Wv,Wg} in one dispatch ---------
__global__ __launch_bounds__(256) void gemm_proj(const u16* __restrict__ A,
                                                 const u16* __restrict__ BtQ,
                                                 const u16* __restrict__ BtK,
                                                 const u16* __restrict__ BtV,
                                                 const u16* __restrict__ BtG,
                                                 float* __restrict__ Cq,
                                                 float* __restrict__ Ck,
                                                 float* __restrict__ Cv,
                                                 float* __restrict__ Cg) {
    __shared__ __align__(16) u16 Asm[128 * 64];
    __shared__ __align__(16) u16 Bsm[128 * 64];
    // XCD-aware block swizzle (T1): nwg = 25*16 = 400, divisible by 8
    int nwg = gridDim.x * gridDim.y;
    int id = xcd_swz(blockIdx.y * gridDim.x + blockIdx.x, nwg);
    int bx = id % gridDim.x, by = id / gridDim.x;
    const u16* Bt; float* C; int N; int bn;
    if (bx < 16)      { Bt = BtQ; C = Cq; N = 2048; bn = bx * 128; }
    else if (bx < 20) { Bt = BtK; C = Ck; N = 512;  bn = (bx - 16) * 128; }
    else if (bx < 24) { Bt = BtV; C = Cv; N = 512;  bn = (bx - 20) * 128; }
    else              { Bt = BtG; C = Cg; N = 48;   bn = 0; }
    const int K = 2048;
    int t = threadIdx.x, lane = t & 63, w = t >> 6;
    int wm = w >> 1, wn = w & 1;
    int bm = by * 128;
    int lr = lane & 15, hi = lane >> 4;

    f32x4 acc[4][4] = {};
    for (int k0 = 0; k0 < K; k0 += 64) {
        if (k0) __syncthreads();
#pragma unroll
        for (int i = 0; i < 4; ++i) {
            int cflat = i * 256 + t;
            int m = cflat >> 3;
            int g = cflat & 7;
            int gl = g ^ (m & 7);
            unsigned lofs = (unsigned)((i * 256 + (t & ~63)) * 16);
            gload16(A + (size_t)(bm + m) * K + k0 + gl * 8, (char*)Asm + lofs);
            gload16(Bt + (size_t)(bn + m) * K + k0 + gl * 8, (char*)Bsm + lofs);
        }
        __syncthreads();
#pragma unroll
        for (int kk = 0; kk < 2; ++kk) {
            bf16x8 af[4], bf[4];
#pragma unroll
            for (int mi = 0; mi < 4; ++mi) {
                int row = wm * 64 + mi * 16 + lr;
                int g = (kk * 4 + hi) ^ (row & 7);
                af[mi] = *reinterpret_cast<const bf16x8*>(&Asm[row * 64 + g * 8]);
            }
#pragma unroll
            for (int ni = 0; ni < 4; ++ni) {
                int row = wn * 64 + ni * 16 + lr;
                int g = (kk * 4 + hi) ^ (row & 7);
                bf[ni] = *reinterpret_cast<const bf16x8*>(&Bsm[row * 64 + g * 8]);
            }
#pragma unroll
            for (int mi = 0; mi < 4; ++mi)
#pragma unroll
                for (int ni = 0; ni < 4; ++ni)
                    acc[mi][ni] = __builtin_amdgcn_mfma_f32_16x16x32_bf16(af[mi], bf[ni], acc[mi][ni], 0, 0, 0);
        }
    }
#pragma unroll
    for (int mi = 0; mi < 4; ++mi) {
#pragma unroll
        for (int ni = 0; ni < 4; ++ni) {
            int col = bn + wn * 64 + ni * 16 + lr;
            if (col < N) {
#pragma unroll
                for (int r = 0; r < 4; ++r) {
                    int row = bm + wm * 64 + mi * 16 + hi * 4 + r;
                    C[(size_t)row * N + col] = acc[mi][ni][r];
                }
            }
        }
    }
}

// ---------------- compressed K/V build, split-K (16 splits) ----------------
__global__ __launch_bounds__(256) void cmp_kv_split(const u16* __restrict__ Ak,
                                                    const u16* __restrict__ Wkt,
                                                    const u16* __restrict__ Av,
                                                    const u16* __restrict__ Wvt,
                                                    float* __restrict__ partials) {
    __shared__ __align__(16) u16 Asm[128 * 64];
    __shared__ __align__(16) u16 Bsm[128 * 64];
    int z = blockIdx.y, split = blockIdx.x;
    int h = z & 3;
    const u16* A  = (z >> 2) ? Av : Ak;
    const u16* Wt = (z >> 2) ? Wvt : Wkt;
    int t = threadIdx.x, lane = t & 63, w = t >> 6;
    int wm = w >> 1, wn = w & 1;
    int lr = lane & 15, hi = lane >> 4;
    const u16* Wh = Wt + (size_t)h * DD * (KS * DD);

    f32x4 acc[4][4] = {};
    int kbase = split * 256;
    for (int it = 0; it < 4; ++it) {
        int k0 = kbase + it * 64;
        if (it) __syncthreads();
        int roff = k0 >> 7;
        int dbase = ((k0 >> 6) & 1) * 64;
#pragma unroll
        for (int i = 0; i < 4; ++i) {
            int cflat = i * 256 + t;
            int m = cflat >> 3;
            int g = cflat & 7;
            int gl = g ^ (m & 7);
            unsigned lofs = (unsigned)((i * 256 + (t & ~63)) * 16);
            int nr = (m < NCMP) ? m : (NCMP - 1);   // clamp pad row
            gload16(A + ((size_t)(nr * KSTRIDE + roff) * HKV + h) * DD + dbase + gl * 8,
                    (char*)Asm + lofs);
            gload16(Wh + (size_t)m * (KS * DD) + k0 + gl * 8, (char*)Bsm + lofs);
        }
        __syncthreads();
#pragma unroll
        for (int kk = 0; kk < 2; ++kk) {
            bf16x8 af[4], bf[4];
#pragma unroll
            for (int mi = 0; mi < 4; ++mi) {
                int row = wm * 64 + mi * 16 + lr;
                int g = (kk * 4 + hi) ^ (row & 7);
                af[mi] = *reinterpret_cast<const bf16x8*>(&Asm[row * 64 + g * 8]);
            }
#pragma unroll
            for (int ni = 0; ni < 4; ++ni) {
                int row = wn * 64 + ni * 16 + lr;
                int g = (kk * 4 + hi) ^ (row & 7);
                bf[ni] = *reinterpret_cast<const bf16x8*>(&Bsm[row * 64 + g * 8]);
            }
#pragma unroll
            for (int mi = 0; mi < 4; ++mi)
#pragma unroll
                for (int ni = 0; ni < 4; ++ni)
                    acc[mi][ni] = __builtin_amdgcn_mfma_f32_16x16x32_bf16(af[mi], bf[ni], acc[mi][ni], 0, 0, 0);
        }
    }
    float* Cout = partials + ((size_t)(z * 16 + split)) * 128 * 128;
#pragma unroll
    for (int mi = 0; mi < 4; ++mi)
#pragma unroll
        for (int ni = 0; ni < 4; ++ni) {
            int col = wn * 64 + ni * 16 + lr;
#pragma unroll
            for (int r = 0; r < 4; ++r) {
                int row = wm * 64 + mi * 16 + hi * 4 + r;
                Cout[(size_t)row * 128 + col] = acc[mi][ni][r];
            }
        }
}

// reduce 16 splits -> bf16 ck [h][n][d] and bf16 cvT [h][d][n]
__global__ void cmp_kv_reduce(const float* __restrict__ partials,
                              u16* __restrict__ ckbf, u16* __restrict__ cvtbf) {
    int row = blockIdx.x, z = blockIdx.y, col = threadIdx.x; // 128 threads
    float s = 0.f;
#pragma unroll
    for (int sp = 0; sp < 16; ++sp)
        s += partials[(((size_t)z * 16 + sp) * 128 + row) * 128 + col];
    if (z < 4) ckbf[((size_t)z * 128 + row) * 128 + col] = f2bf(s);
    else       cvtbf[((size_t)(z - 4) * 128 + col) * 128 + row] = f2bf(s);
}

// ---------------- compressed attention via MFMA + block scores + top-8 -------------
__global__ __launch_bounds__(256) void cmp_attn_mfma(
    const u16* __restrict__ qbf,    // [S][HQ][D] bf16, pre-scaled
    const u16* __restrict__ ckbf,   // [HKV][128][128] bf16 (row 127 = pad)
    const u16* __restrict__ cvtbf,  // [HKV][128 d][128 n] bf16
    const float* __restrict__ gate,
    float* __restrict__ o_acc,
    unsigned int* __restrict__ sel) {
    __shared__ __align__(16) u16 Cks[128 * 128];   // 32 KB, swizzled ck
    __shared__ __align__(16) u16 P2[4][16 * 128];  // 16 KB per-wave P
    __shared__ float bs[4][16][16];                // 4 KB block-score partials
    int t = threadIdx.x, lane = t & 63, w = t >> 6;
    int lr = lane & 15, hi = lane >> 4;
    int s0 = blockIdx.x * 16, h = blockIdx.y;
    int hq = h * GG + w;
    int sr = s0 + lr;
    const u16* ckh = ckbf + (size_t)h * 128 * 128;
    const u16* cvh = cvtbf + (size_t)h * 128 * 128;
    bf16x8 qf[4];
#pragma unroll
    for (int ks = 0; ks < 4; ++ks)
        qf[ks] = *reinterpret_cast<const bf16x8*>(
            &qbf[((size_t)sr * HQ + hq) * DD + ks * 32 + hi * 8]);
    // stage ck into LDS: 16 chunks per 128-elem row, pre-swizzled global source
#pragma unroll
    for (int i = 0; i < 8; ++i) {
        int id = i * 256 + t;
        int key = id >> 4, sub = id & 15;
        gload16(ckh + (size_t)key * 128 + ((sub ^ (key & 7)) * 8),
                (char*)Cks + (id & ~63) * 16);
    }
    __syncthreads();
    f32x4 sacc[8] = {};
#pragma unroll
    for (int ks = 0; ks < 4; ++ks)
#pragma unroll
        for (int mt = 0; mt < 8; ++mt) {
            int row = mt * 16 + lr;
            bf16x8 kf = *reinterpret_cast<const bf16x8*>(
                &Cks[row * 128 + (((ks * 4 + hi) ^ (row & 7)) * 8)]);
            sacc[mt] = __builtin_amdgcn_mfma_f32_16x16x32_bf16(kf, qf[ks], sacc[mt], 0, 0, 0);
        }
    int nv = (sr >= 31) ? ((sr - 31) >> 4) + 1 : 0;
    float e[8][4];
    float mx = -1e30f;
#pragma unroll
    for (int mt = 0; mt < 8; ++mt)
#pragma unroll
        for (int r = 0; r < 4; ++r) {
            int n = mt * 16 + hi * 4 + r;
            float x = (n < nv) ? sacc[mt][r] : -1e30f;
            e[mt][r] = x;
            mx = fmaxf(mx, x);
        }
    mx = fmaxf(mx, __shfl_xor(mx, 16, 64));
    mx = fmaxf(mx, __shfl_xor(mx, 32, 64));
    float l = 0.f;
#pragma unroll
    for (int mt = 0; mt < 8; ++mt)
#pragma unroll
        for (int r = 0; r < 4; ++r) {
            int n = mt * 16 + hi * 4 + r;
            float p = (n < nv) ? __expf(e[mt][r] - mx) : 0.f;
            e[mt][r] = p;
            l += p;
        }
    l += __shfl_xor(l, 16, 64);
    l += __shfl_xor(l, 32, 64);
    float invl = (nv > 0) ? 1.f / l : 0.f;
#pragma unroll
    for (int mt = 0; mt < 8; ++mt)
#pragma unroll
        for (int r = 0; r < 4; ++r) e[mt][r] *= invl;
#pragma unroll
    for (int mt = 0; mt < 8; ++mt) {
        bf16x4 pk;
        pk[0] = (__bf16)e[mt][0]; pk[1] = (__bf16)e[mt][1];
        pk[2] = (__bf16)e[mt][2]; pk[3] = (__bf16)e[mt][3];
        int grp = mt * 2 + (hi >> 1);
        int idx = lr * 128 + ((grp ^ (lr & 7)) * 8) + (hi & 1) * 4;
        *reinterpret_cast<bf16x4*>(&P2[w][idx]) = pk;
    }
#pragma unroll
    for (int mt = 0; mt < 8; ++mt) {
        float s4 = e[mt][0] + e[mt][1] + e[mt][2] + e[mt][3];
        float v = s4 + __shfl_xor(s4, 16, 64);
        if (hi == 0) bs[w][lr][mt * 2] = v;
        else if (hi == 2) bs[w][lr][mt * 2 + 1] = v;
    }
    __syncthreads();
    bf16x8 pa[4];
#pragma unroll
    for (int kslot = 0; kslot < 4; ++kslot)
        pa[kslot] = *reinterpret_cast<const bf16x8*>(
            &P2[w][lr * 128 + (((kslot * 4 + hi) ^ (lr & 7)) * 8)]);
    f32x4 Os[8] = {};
#pragma unroll
    for (int nt = 0; nt < 8; ++nt) {
        int d = nt * 16 + lr;
#pragma unroll
        for (int kslot = 0; kslot < 4; ++kslot) {
            bf16x8 bv = *reinterpret_cast<const bf16x8*>(
                &cvh[(size_t)d * 128 + kslot * 32 + hi * 8]);
            Os[nt] = __builtin_amdgcn_mfma_f32_16x16x32_bf16(pa[kslot], bv, Os[nt], 0, 0, 0);
        }
    }
#pragma unroll
    for (int r = 0; r < 4; ++r) {
        int q = hi * 4 + r;
        int srow = s0 + q;
        float g0 = gate[((size_t)srow * HQ + hq) * 3 + 0];
#pragma unroll
        for (int nt = 0; nt < 8; ++nt) {
            size_t idx = ((size_t)srow * HQ + hq) * DD + nt * 16 + lr;
            o_acc[idx] = g0 * Os[nt][r];
        }
    }
    if (t < 16) {
        int q = t, s = s0 + q;
        int qblk = s >> 7;
#pragma unroll
        for (int b = 0; b < 16; ++b) {
            bool forced = (b == 0) || (b <= qblk && b > qblk - 2);
            bs[0][q][b] = bs[0][q][b] + bs[1][q][b] + bs[2][q][b] + bs[3][q][b]
                          + (forced ? 1e9f : 0.f);
        }
        unsigned int mask = 0;
        for (int it = 0; it < TOPK; ++it) {
            int arg = 0; float best = bs[0][q][0];
            for (int b = 1; b < 16; ++b) {
                float x = bs[0][q][b];
                if (x > best) { best = x; arg = b; }
            }
            mask |= 1u << arg;
            bs[0][q][arg] = -1e38f;
        }
        sel[s * HKV + h] = mask;
    }
}

// ---------------- selected + windowed attention, MFMA flash (GQA: 4 heads/block) ----
// Round-11/13 measured-stable version (VGPR 84, LDS 48.5 KB, 3 blocks/CU, no spill).
// Epilogue reads cmp's f32 o_acc and writes bf16 out directly.
__global__ __launch_bounds__(256, 3) void sel_win_mfma(
    const u16* __restrict__ qbf,   // [S][HQ][D] bf16, pre-scaled by 1/sqrt(D)
    const u16* __restrict__ kbf,   // [S][HKV][D] bf16
    const u16* __restrict__ vtbf,  // [HKV][D][S]  bf16 (transposed V)
    const float* __restrict__ gate,
    const unsigned int* __restrict__ sel,
    const float* __restrict__ oacc, // [S][HQ][D] f32 (g0*O_cmp)
    u16* __restrict__ outb) {       // [S][HQ][D] bf16
    __shared__ __align__(16) u16 Ks[64 * 128];          // [key][d-group swizzled]
    __shared__ __align__(16) u16 Vs[128 * 64];          // [d][key-group swizzled]
    __shared__ __align__(16) u16 P2[4][2][16 * 64];     // per-wave, per-plane P[q][key swz]
    __shared__ unsigned int sml[16];
    int t = threadIdx.x, lane = t & 63, w = t >> 6;
    int lr = lane & 15, hi = lane >> 4;
    int s0 = (gridDim.x - 1 - blockIdx.x) * 16;         // heavy tiles first
    int h = blockIdx.y;
    int hq = h * GG + w;
    int sr = s0 + lr;             // q row this lane handles in softmax role
    if (t < 16) sml[t] = sel[(s0 + t) * HKV + h];
    bf16x8 qf[4];
#pragma unroll
    for (int ks = 0; ks < 4; ++ks)
        qf[ks] = *reinterpret_cast<const bf16x8*>(
            &qbf[((size_t)(s0 + lr) * HQ + hq) * DD + ks * 32 + hi * 8]);
    __syncthreads();
    unsigned mymask = sml[lr];
    unsigned orMask = 0;
#pragma unroll
    for (int i = 0; i < 16; ++i) orMask |= sml[i];
    float m_u = -1e30f, l_s = 0.f, l_w = 0.f;
    f32x4 Os[8] = {}, Ow[8] = {};
    int smax = s0 + 15;
    const u16* vbase = vtbf + (size_t)h * DD * SS;

    for (int kb = 0; kb * 128 <= smax; ++kb) {
        bool needSel = (orMask >> kb) & 1u;
        bool selbit = needSel && ((mymask >> kb) & 1u);
        for (int half = 0; half < 2; ++half) {
            int hst = kb * 128 + half * 64;
            if (hst > smax) break;
            bool hWin = (hst + 63 >= s0 - (WINSZ - 1));
            if (!(needSel || hWin)) continue;
            __syncthreads();   // prior iteration's PV done with Ks/Vs
#pragma unroll
            for (int i = 0; i < 4; ++i) {
                int id = i * 256 + t;
                int key = id >> 4, dq = id & 15;
                gload16(kbf + ((size_t)(hst + key) * HKV + h) * DD + ((dq ^ (key & 7)) * 8),
                        (char*)Ks + (id & ~63) * 16);
                int d = id >> 3, kq = id & 7;
                gload16(vbase + (size_t)d * SS + hst + ((kq ^ (d & 7)) * 8),
                        (char*)Vs + (id & ~63) * 16);
            }
            __syncthreads();   // drain vmcnt; staging visible
            f32x4 sacc[4] = {};
            __builtin_amdgcn_s_setprio(1);
#pragma unroll
            for (int ks = 0; ks < 4; ++ks) {
#pragma unroll
                for (int mt = 0; mt < 4; ++mt) {
                    int key = mt * 16 + lr;
                    bf16x8 kf = *reinterpret_cast<const bf16x8*>(
                        &Ks[key * 128 + (((ks * 4 + hi) ^ (key & 7)) * 8)]);
                    sacc[mt] = __builtin_amdgcn_mfma_f32_16x16x32_bf16(kf, qf[ks], sacc[mt], 0, 0, 0);
                }
            }
            __builtin_amdgcn_s_setprio(0);
            // shared-max softmax over the union mask
            float e4[4][4];
            float mx = -1e30f;
#pragma unroll
            for (int mt = 0; mt < 4; ++mt)
#pragma unroll
                for (int r = 0; r < 4; ++r) {
                    int key = hst + mt * 16 + hi * 4 + r;
                    bool vS = selbit && (key <= sr);
                    bool vW = hWin && (key <= sr) && (key > sr - WINSZ);
                    float e = (vS || vW) ? sacc[mt][r] : -1e30f;
                    e4[mt][r] = e;
                    mx = fmaxf(mx, e);
                }
            mx = fmaxf(mx, __shfl_xor(mx, 16, 64));
            mx = fmaxf(mx, __shfl_xor(mx, 32, 64));
            if (!__all(mx - m_u <= 8.f)) {
                float newm = fmaxf(m_u, mx);
                float corr = __expf(m_u - newm);
                m_u = newm;
                l_s *= corr; l_w *= corr;
#pragma unroll
                for (int r = 0; r < 4; ++r) {
                    float c2 = __shfl(corr, hi * 4 + r, 64);
#pragma unroll
                    for (int nt = 0; nt < 8; ++nt) { Os[nt][r] *= c2; Ow[nt][r] *= c2; }
                }
            }
            float lsA = 0.f, lwA = 0.f;
#pragma unroll
            for (int mt = 0; mt < 4; ++mt)
#pragma unroll
                for (int r = 0; r < 4; ++r) {
                    int key = hst + mt * 16 + hi * 4 + r;
                    bool vS = selbit && (key <= sr);
                    bool vW = hWin && (key <= sr) && (key > sr - WINSZ);
                    float e = (vS || vW) ? __expf(e4[mt][r] - m_u) : 0.f;
                    e4[mt][r] = e;
                    lsA += vS ? e : 0.f;
                    lwA += vW ? e : 0.f;
                }
            lsA += __shfl_xor(lsA, 16, 64); lsA += __shfl_xor(lsA, 32, 64);
            lwA += __shfl_xor(lwA, 16, 64); lwA += __shfl_xor(lwA, 32, 64);
            l_s += lsA; l_w += lwA;
            if (needSel) {
#pragma unroll
                for (int mt = 0; mt < 4; ++mt) {
                    bf16x4 pk;
#pragma unroll
                    for (int r = 0; r < 4; ++r) {
                        int key = hst + mt * 16 + hi * 4 + r;
                        bool vS = selbit && (key <= sr);
                        pk[r] = (__bf16)(vS ? e4[mt][r] : 0.f);
                    }
                    int grp = mt * 2 + (hi >> 1);
                    int idx = lr * 64 + ((grp ^ (lr & 7)) * 8) + (hi & 1) * 4;
                    *reinterpret_cast<bf16x4*>(&P2[w][0][idx]) = pk;
                }
            }
            if (hWin) {
#pragma unroll
                for (int mt = 0; mt < 4; ++mt) {
                    bf16x4 pk;
#pragma unroll
                    for (int r = 0; r < 4; ++r) {
                        int key = hst + mt * 16 + hi * 4 + r;
                        bool vW = (key <= sr) && (key > sr - WINSZ);
                        pk[r] = (__bf16)(vW ? e4[mt][r] : 0.f);
                    }
                    int grp = mt * 2 + (hi >> 1);
                    int idx = lr * 64 + ((grp ^ (lr & 7)) * 8) + (hi & 1) * 4;
                    *reinterpret_cast<bf16x4*>(&P2[w][1][idx]) = pk;
                }
            }
            bf16x8 pas0, pas1, paw0, paw1;
            if (needSel) {
                pas0 = *reinterpret_cast<const bf16x8*>(&P2[w][0][lr * 64 + (((0 + hi) ^ (lr & 7)) * 8)]);
                pas1 = *reinterpret_cast<const bf16x8*>(&P2[w][0][lr * 64 + (((4 + hi) ^ (lr & 7)) * 8)]);
            }
            if (hWin) {
                paw0 = *reinterpret_cast<const bf16x8*>(&P2[w][1][lr * 64 + (((0 + hi) ^ (lr & 7)) * 8)]);
                paw1 = *reinterpret_cast<const bf16x8*>(&P2[w][1][lr * 64 + (((4 + hi) ^ (lr & 7)) * 8)]);
            }
            __builtin_amdgcn_s_setprio(1);
#pragma unroll
            for (int nt = 0; nt < 8; ++nt) {
                int d = nt * 16 + lr;
                bf16x8 bv0 = *reinterpret_cast<const bf16x8*>(&Vs[d * 64 + (((0 + hi) ^ (d & 7)) * 8)]);
                bf16x8 bv1 = *reinterpret_cast<const bf16x8*>(&Vs[d * 64 + (((4 + hi) ^ (d & 7)) * 8)]);
                if (needSel) {
                    Os[nt] = __builtin_amdgcn_mfma_f32_16x16x32_bf16(pas0, bv0, Os[nt], 0, 0, 0);
                    Os[nt] = __builtin_amdgcn_mfma_f32_16x16x32_bf16(pas1, bv1, Os[nt], 0, 0, 0);
                }
                if (hWin) {
                    Ow[nt] = __builtin_amdgcn_mfma_f32_16x16x32_bf16(paw0, bv0, Ow[nt], 0, 0, 0);
                    Ow[nt] = __builtin_amdgcn_mfma_f32_16x16x32_bf16(paw1, bv1, Ow[nt], 0, 0, 0);
                }
            }
            __builtin_amdgcn_s_setprio(0);
        }
    }
    // epilogue: rows q = hi*4+r, cols d = nt*16+lr; combine with cmp (f32) -> bf16
    float invls = (l_s > 0.f) ? 1.f / l_s : 0.f;
    float invlw = (l_w > 0.f) ? 1.f / l_w : 0.f;
#pragma unroll
    for (int r = 0; r < 4; ++r) {
        int q = hi * 4 + r;
        int srow = s0 + q;
        float a1 = gate[((size_t)srow * HQ + hq) * 3 + 1] * __shfl(invls, q, 64);
        float a2 = gate[((size_t)srow * HQ + hq) * 3 + 2] * __shfl(invlw, q, 64);
#pragma unroll
        for (int nt = 0; nt < 8; ++nt) {
            size_t idx = ((size_t)srow * HQ + hq) * DD + nt * 16 + lr;
            outb[idx] = f2bf(oacc[idx] + a1 * Os[nt][r] + a2 * Ow[nt][r]);
        }
    }
}

extern "C" void kernel_launch(void* const* d_in, const int* in_sizes, int n_in,
                              void* d_out, int out_size, void* d_ws, size_t ws_size,
                              hipStream_t stream) {
    const float* x   = (const float*)d_in[0];
    const float* Wq  = (const float*)d_in[1];
    const float* Wk  = (const float*)d_in[2];
    const float* Wv  = (const float*)d_in[3];
    const float* Wo  = (const float*)d_in[4];
    const float* Wg  = (const float*)d_in[5];
    const float* Wck = (const float*)d_in[6];
    const float* Wcv = (const float*)d_in[7];
    float* out = (float*)d_out;
    char* w = (char*)d_ws;
    float* qb   = (float*)(w + 0);          // 16 MiB f32 q GEMM out
    float* kb   = (float*)(w + 16777216);   // 4 MiB f32 k out; later vbf
    float* vb   = (float*)(w + 20971520);   // 4 MiB f32 v out
    float* g3   = (float*)(w + 25165824);   // gates
    u16* ckbf   = (u16*)(w + 25559040);     // [4][128][128] bf16 = 128 KiB
    u16* cvtbf  = (u16*)(w + 25819136);     // [4][128 d][128 n] bf16 = 128 KiB
    unsigned int* selb = (unsigned int*)(w + 26079232);
    float* cost = (float*)(w + 26112000);
    float* sint = (float*)(w + 26636288);
    float* oacc = (float*)(w + 27160576);   // 16 MiB; first 8 MiB doubles as partials
    u16* xb     = (u16*)(w + 43937792);     // 8 MiB; later Wcv_t
    u16* oaccb  = (u16*)(w + 52326400);     // 8 MiB; earlier Wck_t, later attn bf16 out
    u16* Wq_t   = (u16*)(w + 60715008);     // 8 MiB; later qbf
    u16* Wo_t   = (u16*)(w + 69103616);     // 8 MiB
    u16* Wk_t   = (u16*)(w + 77492224);     // 2 MiB; later kbf
    u16* Wv_t   = (u16*)(w + 79589376);     // 2 MiB; later vtbf
    u16* Wg_t   = (u16*)(w + 81686528);     // 0.5 MiB
    u16* qbf = Wq_t;
    u16* kbf = Wk_t;
    u16* vtbf = Wv_t;
    u16* vbf = (u16*)kb;                    // kb dead after rope_k
    u16* Wck_t = oaccb;                     // dead before sel_win writes oaccb
    u16* Wcv_t = xb;                        // xb dead after gemm_proj
    float* partials = oacc;                 // consumed before cmp_attn writes oacc

    hipLaunchKernelGGL(rope_tab, dim3(SS), dim3(64), 0, stream, cost, sint);
    hipLaunchKernelGGL(conv_bf16, dim3(4096), dim3(256), 0, stream, x, xb, SS * HH / 4);
    hipLaunchKernelGGL(convT, dim3(64, 64), dim3(256), 0, stream, Wq, Wq_t, HH, 2048, 2048, 0, 0);
    hipLaunchKernelGGL(convT, dim3(64, 16), dim3(256), 0, stream, Wk, Wk_t, HH, 512, 512, 0, 0);
    hipLaunchKernelGGL(convT, dim3(64, 16), dim3(256), 0, stream, Wv, Wv_t, HH, 512, 512, 0, 0);
    hipLaunchKernelGGL(convT, dim3(64, 4),  dim3(256), 0, stream, Wg, Wg_t, HH, 48, 128, 0, 0);
    hipLaunchKernelGGL(convT, dim3(64, 64), dim3(256), 0, stream, Wo, Wo_t, HQ * DD, 2048, 2048, 0, 0);
    // fused projections
    hipLaunchKernelGGL(gemm_proj, dim3(25, 16), dim3(256), 0, stream,
                       xb, Wq_t, Wk_t, Wv_t, Wg_t, qb, kb, vb, g3);
    // rope + scale + bf16 (q), rope + bf16 (k)
    hipLaunchKernelGGL(rope_bf16, dim3(SS, HQ),  dim3(64), 0, stream, qb, qbf, cost, sint, HQ, 0.08838834764831845f);
    hipLaunchKernelGGL(rope_bf16, dim3(SS, HKV), dim3(64), 0, stream, kb, kbf, cost, sint, HKV, 1.0f);
    hipLaunchKernelGGL(sigmoid_k, dim3((SS * HQ * 3 + 255) / 256), dim3(256), 0, stream, g3, SS * HQ * 3);
    hipLaunchKernelGGL(conv_bf16, dim3(1024), dim3(256), 0, stream, vb, vbf, SS * HKV * DD / 4);
    hipLaunchKernelGGL(conv_vt, dim3(64, 4, 4), dim3(256), 0, stream, vb, vtbf);
    // Wck/Wcv -> transposed bf16 (z-batched over h)
    hipLaunchKernelGGL(convT, dim3(128, 4, 4), dim3(256), 0, stream,
                       Wck, Wck_t, KS * DD, DD, DD, (size_t)KS * DD * DD, (size_t)DD * KS * DD);
    hipLaunchKernelGGL(convT, dim3(128, 4, 4), dim3(256), 0, stream,
                       Wcv, Wcv_t, KS * DD, DD, DD, (size_t)KS * DD * DD, (size_t)DD * KS * DD);
    // compressed K/V: split-K MFMA + reduce to bf16 ck / cvT
    hipLaunchKernelGGL(cmp_kv_split, dim3(16, 8), dim3(256), 0, stream,
                       kbf, Wck_t, vbf, Wcv_t, partials);
    hipLaunchKernelGGL(cmp_kv_reduce, dim3(128, 8), dim3(128), 0, stream,
                       partials, ckbf, cvtbf);
    // attention (two-kernel structure; sel_win combines + writes bf16 out)
    hipLaunchKernelGGL(cmp_attn_mfma, dim3(SS / TQ, HKV), dim3(256), 0, stream,
                       qbf, ckbf, cvtbf, g3, oacc, selb);
    hipLaunchKernelGGL(sel_win_mfma, dim3(SS / TQ, HKV), dim3(256), 0, stream,
                       qbf, kbf, vtbf, g3, selb, oacc, oaccb);
    // output projection
    hipLaunchKernelGGL(gemm_mfma, dim3(16, 16), dim3(256), 0, stream, oaccb, Wo_t, out, 2048, 2048, 2048);
}

// Round 16
// 251.615 us; speedup vs baseline: 1.4990x; 1.0525x over previous
//
#include <hip/hip_runtime.h>
#include <math.h>

#define SS 2048
#define HH 2048
#define HQ 16
#define HKV 4
#define GG 4
#define DD 128
#define KS 32
#define KSTRIDE 16
#define NCMP 127
#define NBLK 16
#define TOPK 8
#define WINSZ 512
#define TQ 16

typedef unsigned short u16;
typedef __bf16 bf16x8 __attribute__((ext_vector_type(8)));
typedef __bf16 bf16x4 __attribute__((ext_vector_type(4)));
typedef float f32x4 __attribute__((ext_vector_type(4)));

__device__ __forceinline__ u16 f2bf(float f) {
    __bf16 b = (__bf16)f;
    return __builtin_bit_cast(u16, b);
}

// XCD-aware bijective swizzle of a flattened block id (nwg must be %8==0)
__device__ __forceinline__ int xcd_swz(int id, int nwg) {
    if (nwg & 7) return id;
    int cpx = nwg >> 3;
    return (id & 7) * cpx + (id >> 3);
}

// ---------------- RoPE tables (llama3-style scaled inv freq) ----------------
__global__ void rope_tab(float* __restrict__ cost, float* __restrict__ sint) {
    int s = blockIdx.x;
    int i = threadIdx.x; // 0..63
    double inv = pow(500000.0, -(double)i / 64.0);
    double wav = 6.283185307179586476925286766559 / inv;
    double inv_s;
    if (wav > 8192.0) inv_s = inv / 8.0;
    else if (wav < 2048.0) inv_s = inv;
    else {
        double sm = (8192.0 / wav - 1.0) / 3.0;
        inv_s = (1.0 - sm) * inv / 8.0 + sm * inv;
    }
    float ang = (float)s * (float)inv_s; // reference computes angle in f32
    cost[s * 64 + i] = cosf(ang);
    sint[s * 64 + i] = sinf(ang);
}

// fused rope for q (scaled) and k, one dispatch: blockIdx.y<HQ -> q, else k
__global__ void rope_qk(const float* __restrict__ qsrc, const float* __restrict__ ksrc,
                        u16* __restrict__ qdst, u16* __restrict__ kdst,
                        const float* __restrict__ cost, const float* __restrict__ sint) {
    int s = blockIdx.x, hh = blockIdx.y, i = threadIdx.x; // i<64
    float c = cost[s * 64 + i], sn = sint[s * 64 + i];
    if (hh < HQ) {
        const float* p = qsrc + ((size_t)s * HQ + hh) * DD;
        u16* d = qdst + ((size_t)s * HQ + hh) * DD;
        const float scale = 0.08838834764831845f;
        float x1 = p[i], x2 = p[i + 64];
        d[i] = f2bf((x1 * c - x2 * sn) * scale);
        d[i + 64] = f2bf((x2 * c + x1 * sn) * scale);
    } else {
        int h = hh - HQ;
        const float* p = ksrc + ((size_t)s * HKV + h) * DD;
        u16* d = kdst + ((size_t)s * HKV + h) * DD;
        float x1 = p[i], x2 = p[i + 64];
        d[i] = f2bf(x1 * c - x2 * sn);
        d[i + 64] = f2bf(x2 * c + x1 * sn);
    }
}

// ---------------- f32 -> bf16 flat convert (vec4) ----------------
__global__ void conv_bf16(const float* __restrict__ in, u16* __restrict__ out, int n4) {
    int i = blockIdx.x * 256 + threadIdx.x;
    if (i < n4) {
        float4 v = ((const float4*)in)[i];
        ushort4 o;
        o.x = f2bf(v.x); o.y = f2bf(v.y); o.z = f2bf(v.z); o.w = f2bf(v.w);
        ((ushort4*)out)[i] = o;
    }
}

// ---------------- v[s][h][d] f32 -> vbf (linear bf16) + vt[h][d][s] bf16, fused ----
__global__ __launch_bounds__(256) void conv_v2(const float* __restrict__ v,
                                               u16* __restrict__ vbf,
                                               u16* __restrict__ vt) {
    __shared__ float tile[32][33];
    int s0 = blockIdx.x * 32, d0 = blockIdx.y * 32, h = blockIdx.z;
    int tx = threadIdx.x & 31, ty = threadIdx.x >> 5;
#pragma unroll
    for (int i = 0; i < 32; i += 8) {
        size_t gi = (size_t)(s0 + ty + i) * (HKV * DD) + h * DD + d0 + tx;
        float val = v[gi];
        tile[ty + i][tx] = val;
        vbf[gi] = f2bf(val);
    }
    __syncthreads();
#pragma unroll
    for (int i = 0; i < 32; i += 8)
        vt[(size_t)h * DD * SS + (size_t)(d0 + ty + i) * SS + s0 + tx] = f2bf(tile[tx][ty + i]);
}

// ---------------- all 5 weight transposes in ONE dispatch ----------------
// W[K=2048][N] f32 -> Bt[Npad][K] bf16. blockIdx.y ranges select the weight.
__global__ __launch_bounds__(256) void convT_all(
    const float* __restrict__ Wq, const float* __restrict__ Wk,
    const float* __restrict__ Wv, const float* __restrict__ Wg,
    const float* __restrict__ Wo,
    u16* __restrict__ BtQ, u16* __restrict__ BtK, u16* __restrict__ BtV,
    u16* __restrict__ BtG, u16* __restrict__ BtO) {
    __shared__ float tile[32][33];
    int by = blockIdx.y;
    const float* W; u16* Bt; int N, Npad, bnb;
    if (by < 64)       { W = Wq; Bt = BtQ; N = 2048; Npad = 2048; bnb = by; }
    else if (by < 80)  { W = Wk; Bt = BtK; N = 512;  Npad = 512;  bnb = by - 64; }
    else if (by < 96)  { W = Wv; Bt = BtV; N = 512;  Npad = 512;  bnb = by - 80; }
    else if (by < 100) { W = Wg; Bt = BtG; N = 48;   Npad = 128;  bnb = by - 96; }
    else               { W = Wo; Bt = BtO; N = 2048; Npad = 2048; bnb = by - 100; }
    const int K = 2048;
    int bk = blockIdx.x * 32, bn = bnb * 32;
    int tx = threadIdx.x & 31, ty = threadIdx.x >> 5;
#pragma unroll
    for (int i = 0; i < 32; i += 8) {
        int k = bk + ty + i, n = bn + tx;
        tile[ty + i][tx] = (n < N) ? W[(size_t)k * N + n] : 0.f;
    }
    __syncthreads();
#pragma unroll
    for (int i = 0; i < 32; i += 8) {
        int n = bn + ty + i, k = bk + tx;
        if (n < Npad) Bt[(size_t)n * K + k] = f2bf(tile[tx][ty + i]);
    }
}

// ---------------- Wck + Wcv transposes in ONE dispatch (z = 0..7) ----------------
__global__ __launch_bounds__(256) void convT_kv(const float* __restrict__ Wck,
                                                const float* __restrict__ Wcv,
                                                u16* __restrict__ Wckt,
                                                u16* __restrict__ Wcvt) {
    __shared__ float tile[32][33];
    int z = blockIdx.z;
    const float* W = (z < 4 ? Wck : Wcv) + (size_t)(z & 3) * KS * DD * DD;
    u16* Bt = (z < 4 ? Wckt : Wcvt) + (size_t)(z & 3) * DD * KS * DD;
    const int K = KS * DD, N = DD;
    int bk = blockIdx.x * 32, bn = blockIdx.y * 32;
    int tx = threadIdx.x & 31, ty = threadIdx.x >> 5;
#pragma unroll
    for (int i = 0; i < 32; i += 8) {
        int k = bk + ty + i, n = bn + tx;
        tile[ty + i][tx] = (n < N) ? W[(size_t)k * N + n] : 0.f;
    }
    __syncthreads();
#pragma unroll
    for (int i = 0; i < 32; i += 8) {
        int n = bn + ty + i, k = bk + tx;
        Bt[(size_t)n * K + k] = f2bf(tile[tx][ty + i]);
    }
}

// ---------------- bf16 MFMA GEMM: C[M,N] = A[M,K] @ Bt[N,K]^T ----------------
__device__ __forceinline__ void gload16(const void* g, void* l) {
    __builtin_amdgcn_global_load_lds((const __attribute__((address_space(1))) void*)g,
                                     (__attribute__((address_space(3))) void*)l, 16, 0, 0);
}

__global__ __launch_bounds__(256) void gemm_mfma(const u16* __restrict__ A,
                                                 const u16* __restrict__ Bt,
                                                 float* __restrict__ C,
                                                 int M, int N, int K) {
    __shared__ __align__(16) u16 Asm[128 * 64];
    __shared__ __align__(16) u16 Bsm[128 * 64];
    int t = threadIdx.x;
    int lane = t & 63;
    int w = t >> 6;
    int wm = w >> 1, wn = w & 1;
    // XCD-aware block swizzle (T1): bijective since nwg % 8 == 0 for our grids
    int nwg = gridDim.x * gridDim.y;
    int id = xcd_swz(blockIdx.y * gridDim.x + blockIdx.x, nwg);
    int bxs = id % gridDim.x, bys = id / gridDim.x;
    int bm = bys * 128, bn = bxs * 128;
    int lr = lane & 15, hi = lane >> 4;

    f32x4 acc[4][4] = {};
    for (int k0 = 0; k0 < K; k0 += 64) {
        if (k0) __syncthreads();
#pragma unroll
        for (int i = 0; i < 4; ++i) {
            int cflat = i * 256 + t;
            int m = cflat >> 3;
            int g = cflat & 7;
            int gl = g ^ (m & 7);
            unsigned lofs = (unsigned)((i * 256 + (t & ~63)) * 16);
            gload16(A + (size_t)(bm + m) * K + k0 + gl * 8, (char*)Asm + lofs);
            gload16(Bt + (size_t)(bn + m) * K + k0 + gl * 8, (char*)Bsm + lofs);
        }
        __syncthreads();
#pragma unroll
        for (int kk = 0; kk < 2; ++kk) {
            bf16x8 af[4], bf[4];
#pragma unroll
            for (int mi = 0; mi < 4; ++mi) {
                int row = wm * 64 + mi * 16 + lr;
                int g = (kk * 4 + hi) ^ (row & 7);
                af[mi] = *reinterpret_cast<const bf16x8*>(&Asm[row * 64 + g * 8]);
            }
#pragma unroll
            for (int ni = 0; ni < 4; ++ni) {
                int row = wn * 64 + ni * 16 + lr;
                int g = (kk * 4 + hi) ^ (row & 7);
                bf[ni] = *reinterpret_cast<const bf16x8*>(&Bsm[row * 64 + g * 8]);
            }
#pragma unroll
            for (int mi = 0; mi < 4; ++mi)
#pragma unroll
                for (int ni = 0; ni < 4; ++ni)
                    acc[mi][ni] = __builtin_amdgcn_mfma_f32_16x16x32_bf16(af[mi], bf[ni], acc[mi][ni], 0, 0, 0);
        }
    }
#pragma unroll
    for (int mi = 0; mi < 4; ++mi) {
#pragma unroll
        for (int ni = 0; ni < 4; ++ni) {
            int col = bn + wn * 64 + ni * 16 + lr;
            if (col < N) {
#pragma unroll
                for (int r = 0; r < 4; ++r) {
                    int row = bm + wm * 64 + mi * 16 + hi * 4 + r;
                    C[(size_t)row * N + col] = acc[mi][ni][r];
                }
            }
        }
    }
}

// ---------------- fused projection GEMM: x @ {Wq,Wk,Wv,Wg} (sigmoid fused on Wg) ---
__global__ __launch_bounds__(256) void gemm_proj(const u16* __restrict__ A,
                                                 const u16* __restrict__ BtQ,
                                                 const u16* __restrict__ BtK,
                                                 const u16* __restrict__ BtV,
                                                 const u16* __restrict__ BtG,
                                                 float* __restrict__ Cq,
                                                 float* __restrict__ Ck,
                                                 float* __restrict__ Cv,
                                                 float* __restrict__ Cg) {
    __shared__ __align__(16) u16 Asm[128 * 64];
    __shared__ __align__(16) u16 Bsm[128 * 64];
    // XCD-aware block swizzle (T1): nwg = 25*16 = 400, divisible by 8
    int nwg = gridDim.x * gridDim.y;
    int id = xcd_swz(blockIdx.y * gridDim.x + blockIdx.x, nwg);
    int bx = id % gridDim.x, by = id / gridDim.x;
    const u16* Bt; float* C; int N; int bn; bool sg = false;
    if (bx < 16)      { Bt = BtQ; C = Cq; N = 2048; bn = bx * 128; }
    else if (bx < 20) { Bt = BtK; C = Ck; N = 512;  bn = (bx - 16) * 128; }
    else if (bx < 24) { Bt = BtV; C = Cv; N = 512;  bn = (bx - 20) * 128; }
    else              { Bt = BtG; C = Cg; N = 48;   bn = 0; sg = true; }
    const int K = 2048;
    int t = threadIdx.x, lane = t & 63, w = t >> 6;
    int wm = w >> 1, wn = w & 1;
    int bm = by * 128;
    int lr = lane & 15, hi = lane >> 4;

    f32x4 acc[4][4] = {};
    for (int k0 = 0; k0 < K; k0 += 64) {
        if (k0) __syncthreads();
#pragma unroll
        for (int i = 0; i < 4; ++i) {
            int cflat = i * 256 + t;
            int m = cflat >> 3;
            int g = cflat & 7;
            int gl = g ^ (m & 7);
            unsigned lofs = (unsigned)((i * 256 + (t & ~63)) * 16);
            gload16(A + (size_t)(bm + m) * K + k0 + gl * 8, (char*)Asm + lofs);
            gload16(Bt + (size_t)(bn + m) * K + k0 + gl * 8, (char*)Bsm + lofs);
        }
        __syncthreads();
#pragma unroll
        for (int kk = 0; kk < 2; ++kk) {
            bf16x8 af[4], bf[4];
#pragma unroll
            for (int mi = 0; mi < 4; ++mi) {
                int row = wm * 64 + mi * 16 + lr;
                int g = (kk * 4 + hi) ^ (row & 7);
                af[mi] = *reinterpret_cast<const bf16x8*>(&Asm[row * 64 + g * 8]);
            }
#pragma unroll
            for (int ni = 0; ni < 4; ++ni) {
                int row = wn * 64 + ni * 16 + lr;
                int g = (kk * 4 + hi) ^ (row & 7);
                bf[ni] = *reinterpret_cast<const bf16x8*>(&Bsm[row * 64 + g * 8]);
            }
#pragma unroll
            for (int mi = 0; mi < 4; ++mi)
#pragma unroll
                for (int ni = 0; ni < 4; ++ni)
                    acc[mi][ni] = __builtin_amdgcn_mfma_f32_16x16x32_bf16(af[mi], bf[ni], acc[mi][ni], 0, 0, 0);
        }
    }
#pragma unroll
    for (int mi = 0; mi < 4; ++mi) {
#pragma unroll
        for (int ni = 0; ni < 4; ++ni) {
            int col = bn + wn * 64 + ni * 16 + lr;
            if (col < N) {
#pragma unroll
                for (int r = 0; r < 4; ++r) {
                    int row = bm + wm * 64 + mi * 16 + hi * 4 + r;
                    float v = acc[mi][ni][r];
                    if (sg) v = 1.f / (1.f + __expf(-v));
                    C[(size_t)row * N + col] = v;
                }
            }
        }
    }
}

// ---------------- compressed K/V build, split-K (16 splits) ----------------
__global__ __launch_bounds__(256) void cmp_kv_split(const u16* __restrict__ Ak,
                                                    const u16* __restrict__ Wkt,
                                                    const u16* __restrict__ Av,
                                                    const u16* __restrict__ Wvt,
                                                    float* __restrict__ partials) {
    __shared__ __align__(16) u16 Asm[128 * 64];
    __shared__ __align__(16) u16 Bsm[128 * 64];
    int z = blockIdx.y, split = blockIdx.x;
    int h = z & 3;
    const u16* A  = (z >> 2) ? Av : Ak;
    const u16* Wt = (z >> 2) ? Wvt : Wkt;
    int t = threadIdx.x, lane = t & 63, w = t >> 6;
    int wm = w >> 1, wn = w & 1;
    int lr = lane & 15, hi = lane >> 4;
    const u16* Wh = Wt + (size_t)h * DD * (KS * DD);

    f32x4 acc[4][4] = {};
    int kbase = split * 256;
    for (int it = 0; it < 4; ++it) {
        int k0 = kbase + it * 64;
        if (it) __syncthreads();
        int roff = k0 >> 7;
        int dbase = ((k0 >> 6) & 1) * 64;
#pragma unroll
        for (int i = 0; i < 4; ++i) {
            int cflat = i * 256 + t;
            int m = cflat >> 3;
            int g = cflat & 7;
            int gl = g ^ (m & 7);
            unsigned lofs = (unsigned)((i * 256 + (t & ~63)) * 16);
            int nr = (m < NCMP) ? m : (NCMP - 1);   // clamp pad row
            gload16(A + ((size_t)(nr * KSTRIDE + roff) * HKV + h) * DD + dbase + gl * 8,
                    (char*)Asm + lofs);
            gload16(Wh + (size_t)m * (KS * DD) + k0 + gl * 8, (char*)Bsm + lofs);
        }
        __syncthreads();
#pragma unroll
        for (int kk = 0; kk < 2; ++kk) {
            bf16x8 af[4], bf[4];
#pragma unroll
            for (int mi = 0; mi < 4; ++mi) {
                int row = wm * 64 + mi * 16 + lr;
                int g = (kk * 4 + hi) ^ (row & 7);
                af[mi] = *reinterpret_cast<const bf16x8*>(&Asm[row * 64 + g * 8]);
            }
#pragma unroll
            for (int ni = 0; ni < 4; ++ni) {
                int row = wn * 64 + ni * 16 + lr;
                int g = (kk * 4 + hi) ^ (row & 7);
                bf[ni] = *reinterpret_cast<const bf16x8*>(&Bsm[row * 64 + g * 8]);
            }
#pragma unroll
            for (int mi = 0; mi < 4; ++mi)
#pragma unroll
                for (int ni = 0; ni < 4; ++ni)
                    acc[mi][ni] = __builtin_amdgcn_mfma_f32_16x16x32_bf16(af[mi], bf[ni], acc[mi][ni], 0, 0, 0);
        }
    }
    float* Cout = partials + ((size_t)(z * 16 + split)) * 128 * 128;
#pragma unroll
    for (int mi = 0; mi < 4; ++mi)
#pragma unroll
        for (int ni = 0; ni < 4; ++ni) {
            int col = wn * 64 + ni * 16 + lr;
#pragma unroll
            for (int r = 0; r < 4; ++r) {
                int row = wm * 64 + mi * 16 + hi * 4 + r;
                Cout[(size_t)row * 128 + col] = acc[mi][ni][r];
            }
        }
}

// reduce 16 splits -> bf16 ck [h][n][d] and bf16 cvT [h][d][n]
__global__ void cmp_kv_reduce(const float* __restrict__ partials,
                              u16* __restrict__ ckbf, u16* __restrict__ cvtbf) {
    int row = blockIdx.x, z = blockIdx.y, col = threadIdx.x; // 128 threads
    float s = 0.f;
#pragma unroll
    for (int sp = 0; sp < 16; ++sp)
        s += partials[(((size_t)z * 16 + sp) * 128 + row) * 128 + col];
    if (z < 4) ckbf[((size_t)z * 128 + row) * 128 + col] = f2bf(s);
    else       cvtbf[((size_t)(z - 4) * 128 + col) * 128 + row] = f2bf(s);
}

// ---------------- compressed attention via MFMA + block scores + top-8 -------------
__global__ __launch_bounds__(256) void cmp_attn_mfma(
    const u16* __restrict__ qbf,    // [S][HQ][D] bf16, pre-scaled
    const u16* __restrict__ ckbf,   // [HKV][128][128] bf16 (row 127 = pad)
    const u16* __restrict__ cvtbf,  // [HKV][128 d][128 n] bf16
    const float* __restrict__ gate,
    float* __restrict__ o_acc,
    unsigned int* __restrict__ sel) {
    __shared__ __align__(16) u16 Cks[128 * 128];   // 32 KB, swizzled ck
    __shared__ __align__(16) u16 P2[4][16 * 128];  // 16 KB per-wave P
    __shared__ float bs[4][16][16];                // 4 KB block-score partials
    int t = threadIdx.x, lane = t & 63, w = t >> 6;
    int lr = lane & 15, hi = lane >> 4;
    int s0 = blockIdx.x * 16, h = blockIdx.y;
    int hq = h * GG + w;
    int sr = s0 + lr;
    const u16* ckh = ckbf + (size_t)h * 128 * 128;
    const u16* cvh = cvtbf + (size_t)h * 128 * 128;
    bf16x8 qf[4];
#pragma unroll
    for (int ks = 0; ks < 4; ++ks)
        qf[ks] = *reinterpret_cast<const bf16x8*>(
            &qbf[((size_t)sr * HQ + hq) * DD + ks * 32 + hi * 8]);
    // stage ck into LDS: 16 chunks per 128-elem row, pre-swizzled global source
#pragma unroll
    for (int i = 0; i < 8; ++i) {
        int id = i * 256 + t;
        int key = id >> 4, sub = id & 15;
        gload16(ckh + (size_t)key * 128 + ((sub ^ (key & 7)) * 8),
                (char*)Cks + (id & ~63) * 16);
    }
    __syncthreads();
    f32x4 sacc[8] = {};
#pragma unroll
    for (int ks = 0; ks < 4; ++ks)
#pragma unroll
        for (int mt = 0; mt < 8; ++mt) {
            int row = mt * 16 + lr;
            bf16x8 kf = *reinterpret_cast<const bf16x8*>(
                &Cks[row * 128 + (((ks * 4 + hi) ^ (row & 7)) * 8)]);
            sacc[mt] = __builtin_amdgcn_mfma_f32_16x16x32_bf16(kf, qf[ks], sacc[mt], 0, 0, 0);
        }
    int nv = (sr >= 31) ? ((sr - 31) >> 4) + 1 : 0;
    float e[8][4];
    float mx = -1e30f;
#pragma unroll
    for (int mt = 0; mt < 8; ++mt)
#pragma unroll
        for (int r = 0; r < 4; ++r) {
            int n = mt * 16 + hi * 4 + r;
            float x = (n < nv) ? sacc[mt][r] : -1e30f;
            e[mt][r] = x;
            mx = fmaxf(mx, x);
        }
    mx = fmaxf(mx, __shfl_xor(mx, 16, 64));
    mx = fmaxf(mx, __shfl_xor(mx, 32, 64));
    float l = 0.f;
#pragma unroll
    for (int mt = 0; mt < 8; ++mt)
#pragma unroll
        for (int r = 0; r < 4; ++r) {
            int n = mt * 16 + hi * 4 + r;
            float p = (n < nv) ? __expf(e[mt][r] - mx) : 0.f;
            e[mt][r] = p;
            l += p;
        }
    l += __shfl_xor(l, 16, 64);
    l += __shfl_xor(l, 32, 64);
    float invl = (nv > 0) ? 1.f / l : 0.f;
#pragma unroll
    for (int mt = 0; mt < 8; ++mt)
#pragma unroll
        for (int r = 0; r < 4; ++r) e[mt][r] *= invl;
#pragma unroll
    for (int mt = 0; mt < 8; ++mt) {
        bf16x4 pk;
        pk[0] = (__bf16)e[mt][0]; pk[1] = (__bf16)e[mt][1];
        pk[2] = (__bf16)e[mt][2]; pk[3] = (__bf16)e[mt][3];
        int grp = mt * 2 + (hi >> 1);
        int idx = lr * 128 + ((grp ^ (lr & 7)) * 8) + (hi & 1) * 4;
        *reinterpret_cast<bf16x4*>(&P2[w][idx]) = pk;
    }
#pragma unroll
    for (int mt = 0; mt < 8; ++mt) {
        float s4 = e[mt][0] + e[mt][1] + e[mt][2] + e[mt][3];
        float v = s4 + __shfl_xor(s4, 16, 64);
        if (hi == 0) bs[w][lr][mt * 2] = v;
        else if (hi == 2) bs[w][lr][mt * 2 + 1] = v;
    }
    __syncthreads();
    bf16x8 pa[4];
#pragma unroll
    for (int kslot = 0; kslot < 4; ++kslot)
        pa[kslot] = *reinterpret_cast<const bf16x8*>(
            &P2[w][lr * 128 + (((kslot * 4 + hi) ^ (lr & 7)) * 8)]);
    f32x4 Os[8] = {};
#pragma unroll
    for (int nt = 0; nt < 8; ++nt) {
        int d = nt * 16 + lr;
#pragma unroll
        for (int kslot = 0; kslot < 4; ++kslot) {
            bf16x8 bv = *reinterpret_cast<const bf16x8*>(
                &cvh[(size_t)d * 128 + kslot * 32 + hi * 8]);
            Os[nt] = __builtin_amdgcn_mfma_f32_16x16x32_bf16(pa[kslot], bv, Os[nt], 0, 0, 0);
        }
    }
#pragma unroll
    for (int r = 0; r < 4; ++r) {
        int q = hi * 4 + r;
        int srow = s0 + q;
        float g0 = gate[((size_t)srow * HQ + hq) * 3 + 0];
#pragma unroll
        for (int nt = 0; nt < 8; ++nt) {
            size_t idx = ((size_t)srow * HQ + hq) * DD + nt * 16 + lr;
            o_acc[idx] = g0 * Os[nt][r];
        }
    }
    if (t < 16) {
        int q = t, s = s0 + q;
        int qblk = s >> 7;
#pragma unroll
        for (int b = 0; b < 16; ++b) {
            bool forced = (b == 0) || (b <= qblk && b > qblk - 2);
            bs[0][q][b] = bs[0][q][b] + bs[1][q][b] + bs[2][q][b] + bs[3][q][b]
                          + (forced ? 1e9f : 0.f);
        }
        unsigned int mask = 0;
        for (int it = 0; it < TOPK; ++it) {
            int arg = 0; float best = bs[0][q][0];
            for (int b = 1; b < 16; ++b) {
                float x = bs[0][q][b];
                if (x > best) { best = x; arg = b; }
            }
            mask |= 1u << arg;
            bs[0][q][arg] = -1e38f;
        }
        sel[s * HKV + h] = mask;
    }
}

// ---------------- selected + windowed attention, MFMA flash (GQA: 4 heads/block) ----
// Round-11/13 measured-stable version (VGPR 84, LDS 48.5 KB, 3 blocks/CU, no spill).
// Epilogue reads cmp's f32 o_acc and writes bf16 out directly.
__global__ __launch_bounds__(256, 3) void sel_win_mfma(
    const u16* __restrict__ qbf,   // [S][HQ][D] bf16, pre-scaled by 1/sqrt(D)
    const u16* __restrict__ kbf,   // [S][HKV][D] bf16
    const u16* __restrict__ vtbf,  // [HKV][D][S]  bf16 (transposed V)
    const float* __restrict__ gate,
    const unsigned int* __restrict__ sel,
    const float* __restrict__ oacc, // [S][HQ][D] f32 (g0*O_cmp)
    u16* __restrict__ outb) {       // [S][HQ][D] bf16
    __shared__ __align__(16) u16 Ks[64 * 128];          // [key][d-group swizzled]
    __shared__ __align__(16) u16 Vs[128 * 64];          // [d][key-group swizzled]
    __shared__ __align__(16) u16 P2[4][2][16 * 64];     // per-wave, per-plane P[q][key swz]
    __shared__ unsigned int sml[16];
    int t = threadIdx.x, lane = t & 63, w = t >> 6;
    int lr = lane & 15, hi = lane >> 4;
    int s0 = (gridDim.x - 1 - blockIdx.x) * 16;         // heavy tiles first
    int h = blockIdx.y;
    int hq = h * GG + w;
    int sr = s0 + lr;             // q row this lane handles in softmax role
    if (t < 16) sml[t] = sel[(s0 + t) * HKV + h];
    bf16x8 qf[4];
#pragma unroll
    for (int ks = 0; ks < 4; ++ks)
        qf[ks] = *reinterpret_cast<const bf16x8*>(
            &qbf[((size_t)(s0 + lr) * HQ + hq) * DD + ks * 32 + hi * 8]);
    __syncthreads();
    unsigned mymask = sml[lr];
    unsigned orMask = 0;
#pragma unroll
    for (int i = 0; i < 16; ++i) orMask |= sml[i];
    float m_u = -1e30f, l_s = 0.f, l_w = 0.f;
    f32x4 Os[8] = {}, Ow[8] = {};
    int smax = s0 + 15;
    const u16* vbase = vtbf + (size_t)h * DD * SS;

    for (int kb = 0; kb * 128 <= smax; ++kb) {
        bool needSel = (orMask >> kb) & 1u;
        bool selbit = needSel && ((mymask >> kb) & 1u);
        for (int half = 0; half < 2; ++half) {
            int hst = kb * 128 + half * 64;
            if (hst > smax) break;
            bool hWin = (hst + 63 >= s0 - (WINSZ - 1));
            if (!(needSel || hWin)) continue;
            __syncthreads();   // prior iteration's PV done with Ks/Vs
#pragma unroll
            for (int i = 0; i < 4; ++i) {
                int id = i * 256 + t;
                int key = id >> 4, dq = id & 15;
                gload16(kbf + ((size_t)(hst + key) * HKV + h) * DD + ((dq ^ (key & 7)) * 8),
                        (char*)Ks + (id & ~63) * 16);
                int d = id >> 3, kq = id & 7;
                gload16(vbase + (size_t)d * SS + hst + ((kq ^ (d & 7)) * 8),
                        (char*)Vs + (id & ~63) * 16);
            }
            __syncthreads();   // drain vmcnt; staging visible
            f32x4 sacc[4] = {};
            __builtin_amdgcn_s_setprio(1);
#pragma unroll
            for (int ks = 0; ks < 4; ++ks) {
#pragma unroll
                for (int mt = 0; mt < 4; ++mt) {
                    int key = mt * 16 + lr;
                    bf16x8 kf = *reinterpret_cast<const bf16x8*>(
                        &Ks[key * 128 + (((ks * 4 + hi) ^ (key & 7)) * 8)]);
                    sacc[mt] = __builtin_amdgcn_mfma_f32_16x16x32_bf16(kf, qf[ks], sacc[mt], 0, 0, 0);
                }
            }
            __builtin_amdgcn_s_setprio(0);
            // shared-max softmax over the union mask
            float e4[4][4];
            float mx = -1e30f;
#pragma unroll
            for (int mt = 0; mt < 4; ++mt)
#pragma unroll
                for (int r = 0; r < 4; ++r) {
                    int key = hst + mt * 16 + hi * 4 + r;
                    bool vS = selbit && (key <= sr);
                    bool vW = hWin && (key <= sr) && (key > sr - WINSZ);
                    float e = (vS || vW) ? sacc[mt][r] : -1e30f;
                    e4[mt][r] = e;
                    mx = fmaxf(mx, e);
                }
            mx = fmaxf(mx, __shfl_xor(mx, 16, 64));
            mx = fmaxf(mx, __shfl_xor(mx, 32, 64));
            if (!__all(mx - m_u <= 8.f)) {
                float newm = fmaxf(m_u, mx);
                float corr = __expf(m_u - newm);
                m_u = newm;
                l_s *= corr; l_w *= corr;
#pragma unroll
                for (int r = 0; r < 4; ++r) {
                    float c2 = __shfl(corr, hi * 4 + r, 64);
#pragma unroll
                    for (int nt = 0; nt < 8; ++nt) { Os[nt][r] *= c2; Ow[nt][r] *= c2; }
                }
            }
            float lsA = 0.f, lwA = 0.f;
#pragma unroll
            for (int mt = 0; mt < 4; ++mt)
#pragma unroll
                for (int r = 0; r < 4; ++r) {
                    int key = hst + mt * 16 + hi * 4 + r;
                    bool vS = selbit && (key <= sr);
                    bool vW = hWin && (key <= sr) && (key > sr - WINSZ);
                    float e = (vS || vW) ? __expf(e4[mt][r] - m_u) : 0.f;
                    e4[mt][r] = e;
                    lsA += vS ? e : 0.f;
                    lwA += vW ? e : 0.f;
                }
            lsA += __shfl_xor(lsA, 16, 64); lsA += __shfl_xor(lsA, 32, 64);
            lwA += __shfl_xor(lwA, 16, 64); lwA += __shfl_xor(lwA, 32, 64);
            l_s += lsA; l_w += lwA;
            if (needSel) {
#pragma unroll
                for (int mt = 0; mt < 4; ++mt) {
                    bf16x4 pk;
#pragma unroll
                    for (int r = 0; r < 4; ++r) {
                        int key = hst + mt * 16 + hi * 4 + r;
                        bool vS = selbit && (key <= sr);
                        pk[r] = (__bf16)(vS ? e4[mt][r] : 0.f);
                    }
                    int grp = mt * 2 + (hi >> 1);
                    int idx = lr * 64 + ((grp ^ (lr & 7)) * 8) + (hi & 1) * 4;
                    *reinterpret_cast<bf16x4*>(&P2[w][0][idx]) = pk;
                }
            }
            if (hWin) {
#pragma unroll
                for (int mt = 0; mt < 4; ++mt) {
                    bf16x4 pk;
#pragma unroll
                    for (int r = 0; r < 4; ++r) {
                        int key = hst + mt * 16 + hi * 4 + r;
                        bool vW = (key <= sr) && (key > sr - WINSZ);
                        pk[r] = (__bf16)(vW ? e4[mt][r] : 0.f);
                    }
                    int grp = mt * 2 + (hi >> 1);
                    int idx = lr * 64 + ((grp ^ (lr & 7)) * 8) + (hi & 1) * 4;
                    *reinterpret_cast<bf16x4*>(&P2[w][1][idx]) = pk;
                }
            }
            bf16x8 pas0, pas1, paw0, paw1;
            if (needSel) {
                pas0 = *reinterpret_cast<const bf16x8*>(&P2[w][0][lr * 64 + (((0 + hi) ^ (lr & 7)) * 8)]);
                pas1 = *reinterpret_cast<const bf16x8*>(&P2[w][0][lr * 64 + (((4 + hi) ^ (lr & 7)) * 8)]);
            }
            if (hWin) {
                paw0 = *reinterpret_cast<const bf16x8*>(&P2[w][1][lr * 64 + (((0 + hi) ^ (lr & 7)) * 8)]);
                paw1 = *reinterpret_cast<const bf16x8*>(&P2[w][1][lr * 64 + (((4 + hi) ^ (lr & 7)) * 8)]);
            }
            __builtin_amdgcn_s_setprio(1);
#pragma unroll
            for (int nt = 0; nt < 8; ++nt) {
                int d = nt * 16 + lr;
                bf16x8 bv0 = *reinterpret_cast<const bf16x8*>(&Vs[d * 64 + (((0 + hi) ^ (d & 7)) * 8)]);
                bf16x8 bv1 = *reinterpret_cast<const bf16x8*>(&Vs[d * 64 + (((4 + hi) ^ (d & 7)) * 8)]);
                if (needSel) {
                    Os[nt] = __builtin_amdgcn_mfma_f32_16x16x32_bf16(pas0, bv0, Os[nt], 0, 0, 0);
                    Os[nt] = __builtin_amdgcn_mfma_f32_16x16x32_bf16(pas1, bv1, Os[nt], 0, 0, 0);
                }
                if (hWin) {
                    Ow[nt] = __builtin_amdgcn_mfma_f32_16x16x32_bf16(paw0, bv0, Ow[nt], 0, 0, 0);
                    Ow[nt] = __builtin_amdgcn_mfma_f32_16x16x32_bf16(paw1, bv1, Ow[nt], 0, 0, 0);
                }
            }
            __builtin_amdgcn_s_setprio(0);
        }
    }
    // epilogue: rows q = hi*4+r, cols d = nt*16+lr; combine with cmp (f32) -> bf16
    float invls = (l_s > 0.f) ? 1.f / l_s : 0.f;
    float invlw = (l_w > 0.f) ? 1.f / l_w : 0.f;
#pragma unroll
    for (int r = 0; r < 4; ++r) {
        int q = hi * 4 + r;
        int srow = s0 + q;
        float a1 = gate[((size_t)srow * HQ + hq) * 3 + 1] * __shfl(invls, q, 64);
        float a2 = gate[((size_t)srow * HQ + hq) * 3 + 2] * __shfl(invlw, q, 64);
#pragma unroll
        for (int nt = 0; nt < 8; ++nt) {
            size_t idx = ((size_t)srow * HQ + hq) * DD + nt * 16 + lr;
            outb[idx] = f2bf(oacc[idx] + a1 * Os[nt][r] + a2 * Ow[nt][r]);
        }
    }
}

extern "C" void kernel_launch(void* const* d_in, const int* in_sizes, int n_in,
                              void* d_out, int out_size, void* d_ws, size_t ws_size,
                              hipStream_t stream) {
    const float* x   = (const float*)d_in[0];
    const float* Wq  = (const float*)d_in[1];
    const float* Wk  = (const float*)d_in[2];
    const float* Wv  = (const float*)d_in[3];
    const float* Wo  = (const float*)d_in[4];
    const float* Wg  = (const float*)d_in[5];
    const float* Wck = (const float*)d_in[6];
    const float* Wcv = (const float*)d_in[7];
    float* out = (float*)d_out;
    char* w = (char*)d_ws;
    float* qb   = (float*)(w + 0);          // 16 MiB f32 q GEMM out
    float* kb   = (float*)(w + 16777216);   // 4 MiB f32 k out; later vbf
    float* vb   = (float*)(w + 20971520);   // 4 MiB f32 v out
    float* g3   = (float*)(w + 25165824);   // gates (sigmoid applied in gemm_proj)
    u16* ckbf   = (u16*)(w + 25559040);     // [4][128][128] bf16 = 128 KiB
    u16* cvtbf  = (u16*)(w + 25819136);     // [4][128 d][128 n] bf16 = 128 KiB
    unsigned int* selb = (unsigned int*)(w + 26079232);
    float* cost = (float*)(w + 26112000);
    float* sint = (float*)(w + 26636288);
    float* oacc = (float*)(w + 27160576);   // 16 MiB; first 8 MiB doubles as partials
    u16* xb     = (u16*)(w + 43937792);     // 8 MiB; later Wcv_t
    u16* oaccb  = (u16*)(w + 52326400);     // 8 MiB; earlier Wck_t, later attn bf16 out
    u16* Wq_t   = (u16*)(w + 60715008);     // 8 MiB; later qbf
    u16* Wo_t   = (u16*)(w + 69103616);     // 8 MiB
    u16* Wk_t   = (u16*)(w + 77492224);     // 2 MiB; later kbf
    u16* Wv_t   = (u16*)(w + 79589376);     // 2 MiB; later vtbf
    u16* Wg_t   = (u16*)(w + 81686528);     // 0.5 MiB
    u16* qbf = Wq_t;
    u16* kbf = Wk_t;
    u16* vtbf = Wv_t;
    u16* vbf = (u16*)kb;                    // kb dead after rope_qk
    u16* Wck_t = oaccb;                     // dead before sel_win writes oaccb
    u16* Wcv_t = xb;                        // xb dead after gemm_proj
    float* partials = oacc;                 // consumed before cmp_attn writes oacc

    hipLaunchKernelGGL(rope_tab, dim3(SS), dim3(64), 0, stream, cost, sint);
    hipLaunchKernelGGL(conv_bf16, dim3(4096), dim3(256), 0, stream, x, xb, SS * HH / 4);
    // all 5 weight transposes in one dispatch
    hipLaunchKernelGGL(convT_all, dim3(64, 164), dim3(256), 0, stream,
                       Wq, Wk, Wv, Wg, Wo, Wq_t, Wk_t, Wv_t, Wg_t, Wo_t);
    // fused projections (sigmoid applied on the Wg output path)
    hipLaunchKernelGGL(gemm_proj, dim3(25, 16), dim3(256), 0, stream,
                       xb, Wq_t, Wk_t, Wv_t, Wg_t, qb, kb, vb, g3);
    // rope + bf16 for q (scaled) and k in one dispatch
    hipLaunchKernelGGL(rope_qk, dim3(SS, HQ + HKV), dim3(64), 0, stream,
                       qb, kb, qbf, kbf, cost, sint);
    // v -> linear bf16 + transposed bf16, one dispatch (runs after rope_qk reads kb)
    hipLaunchKernelGGL(conv_v2, dim3(64, 4, 4), dim3(256), 0, stream, vb, vbf, vtbf);
    // Wck + Wcv transposes in one dispatch
    hipLaunchKernelGGL(convT_kv, dim3(128, 4, 8), dim3(256), 0, stream,
                       Wck, Wcv, Wck_t, Wcv_t);
    // compressed K/V: split-K MFMA + reduce to bf16 ck / cvT
    hipLaunchKernelGGL(cmp_kv_split, dim3(16, 8), dim3(256), 0, stream,
                       kbf, Wck_t, vbf, Wcv_t, partials);
    hipLaunchKernelGGL(cmp_kv_reduce, dim3(128, 8), dim3(128), 0, stream,
                       partials, ckbf, cvtbf);
    // attention (two-kernel structure; sel_win combines + writes bf16 out)
    hipLaunchKernelGGL(cmp_attn_mfma, dim3(SS / TQ, HKV), dim3(256), 0, stream,
                       qbf, ckbf, cvtbf, g3, oacc, selb);
    hipLaunchKernelGGL(sel_win_mfma, dim3(SS / TQ, HKV), dim3(256), 0, stream,
                       qbf, kbf, vtbf, g3, selb, oacc, oaccb);
    // output projection
    hipLaunchKernelGGL(gemm_mfma, dim3(16, 16), dim3(256), 0, stream, oaccb, Wo_t, out, 2048, 2048, 2048);
}